// Round 1
// baseline (1019.590 us; speedup 1.0000x reference)
//
#include <hip/hip_runtime.h>
#include <hip/hip_bf16.h>

// ---------------------------------------------------------------------------
// ImprovedGNN: Linear(16->128)+BN+ReLU -> GAT(2 heads,128)+BN+ReLU
//              -> GAT(1 head,128)+BN+ReLU -> Linear(128->64)+BN+ReLU -> Linear(64->1)
// All fp32. BN stats in double (cancellation protection).
// CSR built once per call, reused by both GAT layers.
// ---------------------------------------------------------------------------

// ---------------- ordered-float encoding for atomicMax on float ------------
__device__ inline unsigned fenc(float f) {
    unsigned u = __float_as_uint(f);
    return (u & 0x80000000u) ? ~u : (u | 0x80000000u);
}
__device__ inline float fdec(unsigned e) {
    unsigned u = (e & 0x80000000u) ? (e & 0x7fffffffu) : ~e;
    return __uint_as_float(u);
}

// ---------------- tiled fp32 GEMM: C[M,Nc] = A[M,K] @ B[K,Nc] (+bias) ------
// BM=64, BN=64, BK=16, 256 threads, 4x4 per thread.
__global__ __launch_bounds__(256) void gemm_f32(
    const float* __restrict__ A, const float* __restrict__ B,
    const float* __restrict__ bias, float* __restrict__ C,
    int M, int Nc, int K)
{
    __shared__ float As[16][68];   // [k][m], row stride 68 floats = 272B (16B mult)
    __shared__ float Bs[16][68];   // [k][n]
    const int t  = threadIdx.x;
    const int m0 = blockIdx.x * 64;
    const int n0 = blockIdx.y * 64;
    const int tx = t & 15;         // col group
    const int ty = t >> 4;         // row group
    const int lar = t >> 2;        // A-tile row 0..63
    const int lac = (t & 3) * 4;   // A-tile col 0,4,8,12
    const int lbr = t >> 4;        // B-tile row 0..15
    const int lbc = (t & 15) * 4;  // B-tile col

    float acc[4][4] = {};
    for (int k0 = 0; k0 < K; k0 += 16) {
        {
            int gr = m0 + lar;
            float4 v = make_float4(0.f, 0.f, 0.f, 0.f);
            if (gr < M) v = *reinterpret_cast<const float4*>(A + (size_t)gr * K + k0 + lac);
            As[lac + 0][lar] = v.x; As[lac + 1][lar] = v.y;
            As[lac + 2][lar] = v.z; As[lac + 3][lar] = v.w;
        }
        {
            float4 v = *reinterpret_cast<const float4*>(B + (size_t)(k0 + lbr) * Nc + n0 + lbc);
            *reinterpret_cast<float4*>(&Bs[lbr][lbc]) = v;
        }
        __syncthreads();
#pragma unroll
        for (int kk = 0; kk < 16; ++kk) {
            float a[4], b[4];
            *reinterpret_cast<float4*>(a) = *reinterpret_cast<const float4*>(&As[kk][ty * 4]);
            *reinterpret_cast<float4*>(b) = *reinterpret_cast<const float4*>(&Bs[kk][tx * 4]);
#pragma unroll
            for (int i = 0; i < 4; ++i)
#pragma unroll
                for (int j = 0; j < 4; ++j)
                    acc[i][j] = fmaf(a[i], b[j], acc[i][j]);
        }
        __syncthreads();
    }
    float bj[4] = {0.f, 0.f, 0.f, 0.f};
    if (bias) *reinterpret_cast<float4*>(bj) = *reinterpret_cast<const float4*>(bias + n0 + tx * 4);
#pragma unroll
    for (int i = 0; i < 4; ++i) {
        int row = m0 + ty * 4 + i;
        if (row < M) {
            float4 v = make_float4(acc[i][0] + bj[0], acc[i][1] + bj[1],
                                   acc[i][2] + bj[2], acc[i][3] + bj[3]);
            *reinterpret_cast<float4*>(C + (size_t)row * Nc + n0 + tx * 4) = v;
        }
    }
}

// ---------------- BN stats: per-column sum & sumsq in double ---------------
template<int C>
__global__ __launch_bounds__(256) void bn_stats(const float* __restrict__ y,
                                                double* __restrict__ sums, int Nn)
{
    constexpr int R = (256 / C) < 1 ? 1 : (256 / C);
    const int t = threadIdx.x;
    const int col = (C >= 256) ? t : (t % C);
    const int r0  = (C >= 256) ? 0 : (t / C);
    double s = 0.0, s2 = 0.0;
    for (int row = blockIdx.x * R + r0; row < Nn; row += gridDim.x * R) {
        float v = y[(size_t)row * C + col];
        s += v; s2 += (double)v * (double)v;
    }
    __shared__ double ls[256], ls2[256];
    ls[t] = s; ls2[t] = s2;
    __syncthreads();
    if (t < C) {
#pragma unroll
        for (int k = 1; k < R; ++k) { s += ls[t + k * C]; s2 += ls2[t + k * C]; }
        atomicAdd(&sums[col], s);
        atomicAdd(&sums[C + col], s2);
    }
}

template<int C>
__global__ void bn_fin(const double* __restrict__ sums, const float* __restrict__ g,
                       const float* __restrict__ be, float* __restrict__ sc,
                       float* __restrict__ sh, int Nn)
{
    int c = threadIdx.x;
    if (c < C) {
        double mean = sums[c] / Nn;
        double var  = sums[C + c] / Nn - mean * mean;
        if (var < 0.0) var = 0.0;
        double s = (double)g[c] / sqrt(var + 1e-5);
        sc[c] = (float)s;
        sh[c] = (float)((double)be[c] - mean * s);
    }
}

template<int C>
__global__ __launch_bounds__(256) void bn_apply_relu(float* __restrict__ y,
                                                     const float* __restrict__ sc,
                                                     const float* __restrict__ sh, int total4)
{
    int i = blockIdx.x * blockDim.x + threadIdx.x;
    int stride = gridDim.x * blockDim.x;
    for (; i < total4; i += stride) {
        float4 v = reinterpret_cast<float4*>(y)[i];
        int cb = (i * 4) % C;
        float4 s = *reinterpret_cast<const float4*>(sc + cb);
        float4 h = *reinterpret_cast<const float4*>(sh + cb);
        v.x = fmaxf(fmaf(v.x, s.x, h.x), 0.f);
        v.y = fmaxf(fmaf(v.y, s.y, h.y), 0.f);
        v.z = fmaxf(fmaf(v.z, s.z, h.z), 0.f);
        v.w = fmaxf(fmaf(v.w, s.w, h.w), 0.f);
        reinterpret_cast<float4*>(y)[i] = v;
    }
}

// ---------------- attention scores per node ---------------------------------
template<int HEADS>
__global__ __launch_bounds__(256) void att_scores(
    const float* __restrict__ g, const float* __restrict__ att_s,
    const float* __restrict__ att_d, float* __restrict__ a_s,
    float* __restrict__ a_d, int Nn)
{
    constexpr int C = HEADS * 128;
    constexpr int VEC = C / 64;
    constexpr int GROUP = 128 / VEC;   // lanes per head
    int wid  = (blockIdx.x * 256 + threadIdx.x) >> 6;
    int lane = threadIdx.x & 63;
    if (wid >= Nn) return;
    float ps = 0.f, pd = 0.f;
    const float* gp = g + (size_t)wid * C + lane * VEC;
#pragma unroll
    for (int j = 0; j < VEC; ++j) {
        float v = gp[j];
        ps += v * att_s[lane * VEC + j];
        pd += v * att_d[lane * VEC + j];
    }
    for (int off = 1; off < GROUP; off <<= 1) {
        ps += __shfl_xor(ps, off, 64);
        pd += __shfl_xor(pd, off, 64);
    }
    if ((lane & (GROUP - 1)) == 0) {
        int head = (lane * VEC) >> 7;
        a_s[wid * HEADS + head] = ps;
        a_d[wid * HEADS + head] = pd;
    }
}

// ---------------- CSR build -------------------------------------------------
__global__ void count_edges(const int* __restrict__ ei, int E, int Nn, int* __restrict__ counts)
{
    int k = blockIdx.x * blockDim.x + threadIdx.x;
    if (k >= E + Nn) return;
    int d = (k < E) ? ei[E + k] : (k - E);
    atomicAdd(&counts[d], 1);
}

__global__ void scan_chunk_sum(const int* __restrict__ counts, int Nn, int* __restrict__ csum)
{
    __shared__ int sh[256];
    int i = blockIdx.x * 256 + threadIdx.x;
    sh[threadIdx.x] = (i < Nn) ? counts[i] : 0;
    __syncthreads();
    for (int off = 128; off > 0; off >>= 1) {
        if (threadIdx.x < off) sh[threadIdx.x] += sh[threadIdx.x + off];
        __syncthreads();
    }
    if (threadIdx.x == 0) csum[blockIdx.x] = sh[0];
}

__global__ void scan_chunks(const int* __restrict__ csum, int nchunks, int* __restrict__ coff,
                            int* __restrict__ offsets, int Nn, int Etot)
{
    __shared__ int sh[256];
    int t = threadIdx.x;
    int v = (t < nchunks) ? csum[t] : 0;
    sh[t] = v;
    __syncthreads();
    for (int off = 1; off < 256; off <<= 1) {
        int add = (t >= off) ? sh[t - off] : 0;
        __syncthreads();
        sh[t] += add;
        __syncthreads();
    }
    if (t < nchunks) coff[t] = sh[t] - v;   // exclusive
    if (t == 0) offsets[Nn] = Etot;
}

__global__ void scan_final(const int* __restrict__ counts, int Nn,
                           const int* __restrict__ coff, int* __restrict__ offsets)
{
    __shared__ int sh[256];
    int t = threadIdx.x;
    int i = blockIdx.x * 256 + t;
    int v = (i < Nn) ? counts[i] : 0;
    sh[t] = v;
    __syncthreads();
    for (int off = 1; off < 256; off <<= 1) {
        int add = (t >= off) ? sh[t - off] : 0;
        __syncthreads();
        sh[t] += add;
        __syncthreads();
    }
    if (i < Nn) offsets[i] = coff[blockIdx.x] + sh[t] - v;
}

__global__ void scatter_edges(const int* __restrict__ ei, int E, int Nn,
                              const int* __restrict__ offsets, int* __restrict__ cursor,
                              int* __restrict__ csr_src, int* __restrict__ csr_eid)
{
    int k = blockIdx.x * blockDim.x + threadIdx.x;
    if (k >= E + Nn) return;
    int s, d;
    if (k < E) { s = ei[k]; d = ei[E + k]; } else { s = k - E; d = k - E; }
    int pos = offsets[d] + atomicAdd(&cursor[d], 1);
    csr_src[pos] = s;
    csr_eid[pos] = k;
}

// ---------------- edge passes -----------------------------------------------
template<int HEADS>
__global__ void edge_scores(const int* __restrict__ ei, int E, int Nn,
                            const float* __restrict__ a_s, const float* __restrict__ a_d,
                            float* __restrict__ eraw, unsigned* __restrict__ emax)
{
    int k = blockIdx.x * blockDim.x + threadIdx.x;
    if (k >= E + Nn) return;
    int s, d;
    if (k < E) { s = ei[k]; d = ei[E + k]; } else { s = d = k - E; }
#pragma unroll
    for (int h = 0; h < HEADS; ++h) {
        float e = a_s[s * HEADS + h] + a_d[d * HEADS + h];
        e = (e > 0.f) ? e : 0.2f * e;
        eraw[(size_t)k * HEADS + h] = e;
        atomicMax(&emax[d * HEADS + h], fenc(e));
    }
}

template<int HEADS>
__global__ void edge_exp(const int* __restrict__ ei, int E, int Nn,
                         const unsigned* __restrict__ emax, float* __restrict__ ee)
{
    int k = blockIdx.x * blockDim.x + threadIdx.x;
    if (k >= E + Nn) return;
    int d = (k < E) ? ei[E + k] : (k - E);
#pragma unroll
    for (int h = 0; h < HEADS; ++h) {
        float m = fdec(emax[d * HEADS + h]);
        ee[(size_t)k * HEADS + h] = expf(ee[(size_t)k * HEADS + h] - m);
    }
}

// ---------------- GAT aggregation: one wave per node ------------------------
template<int C, int HEADS>
__global__ __launch_bounds__(256) void gat_agg(
    const float* __restrict__ hfeat, const float* __restrict__ ee,
    const int* __restrict__ offsets, const int* __restrict__ csr_src,
    const int* __restrict__ csr_eid, const float* __restrict__ bias,
    float* __restrict__ out, int Nn)
{
    constexpr int VEC = C / 64;
    int wid  = (blockIdx.x * 256 + threadIdx.x) >> 6;
    int lane = threadIdx.x & 63;
    if (wid >= Nn) return;
    int head = (lane * VEC) >> 7;
    int beg = offsets[wid], end = offsets[wid + 1];
    float acc[VEC] = {};
    float wsum = 0.f;
    for (int p = beg; p < end; ++p) {
        int srcn = csr_src[p];
        int eid  = csr_eid[p];
        float w  = ee[(size_t)eid * HEADS + head];
        const float* hp = hfeat + (size_t)srcn * C + lane * VEC;
        if constexpr (VEC == 4) {
            float4 hv = *reinterpret_cast<const float4*>(hp);
            acc[0] += w * hv.x; acc[1] += w * hv.y;
            acc[2] += w * hv.z; acc[3] += w * hv.w;
        } else {
            float2 hv = *reinterpret_cast<const float2*>(hp);
            acc[0] += w * hv.x; acc[1] += w * hv.y;
        }
        wsum += w;
    }
    float inv = 1.f / (wsum + 1e-16f);
    float* op = out + (size_t)wid * C + lane * VEC;
#pragma unroll
    for (int j = 0; j < VEC; ++j) op[j] = acc[j] * inv + bias[lane * VEC + j];
}

// ---------------- final dot (N,64)@(64,1) -----------------------------------
__global__ __launch_bounds__(256) void final_dot(const float* __restrict__ h3,
                                                 const float* __restrict__ w,
                                                 const float* __restrict__ b,
                                                 float* __restrict__ out, int Nn)
{
    int wid  = (blockIdx.x * 256 + threadIdx.x) >> 6;
    int lane = threadIdx.x & 63;
    if (wid >= Nn) return;
    float v = h3[(size_t)wid * 64 + lane] * w[lane];
    for (int off = 32; off > 0; off >>= 1) v += __shfl_xor(v, off, 64);
    if (lane == 0) out[wid] = v + b[0];
}

// ---------------------------------------------------------------------------
extern "C" void kernel_launch(void* const* d_in, const int* in_sizes, int n_in,
                              void* d_out, int out_size, void* d_ws, size_t ws_size,
                              hipStream_t stream)
{
    const float* x     = (const float*)d_in[0];
    const int*   ei    = (const int*)d_in[1];
    const float* W_in  = (const float*)d_in[2];
    const float* b_in  = (const float*)d_in[3];
    const float* g0    = (const float*)d_in[4];
    const float* be0   = (const float*)d_in[5];
    const float* W1    = (const float*)d_in[6];
    const float* as1   = (const float*)d_in[7];
    const float* ad1   = (const float*)d_in[8];
    const float* bias1 = (const float*)d_in[9];
    const float* g1    = (const float*)d_in[10];
    const float* be1   = (const float*)d_in[11];
    const float* W2    = (const float*)d_in[12];
    const float* as2   = (const float*)d_in[13];
    const float* ad2   = (const float*)d_in[14];
    const float* bias2 = (const float*)d_in[15];
    const float* g2    = (const float*)d_in[16];
    const float* be2   = (const float*)d_in[17];
    const float* Wf1   = (const float*)d_in[18];
    const float* bf1   = (const float*)d_in[19];
    const float* gf    = (const float*)d_in[20];
    const float* bef   = (const float*)d_in[21];
    const float* Wf2   = (const float*)d_in[22];
    const float* bf2   = (const float*)d_in[23];

    const int N    = in_sizes[0] / 16;     // 50000
    const int E    = in_sizes[1] / 2;      // 800000
    const int Etot = E + N;                // with self loops

    // ---- workspace layout (256B aligned blocks) ----
    char* ws = (char*)d_ws;
    size_t off = 0;
    auto alloc = [&](size_t bytes) {
        size_t o = off;
        off += (bytes + 255) & ~(size_t)255;
        return o;
    };
    float* buf0 = (float*)(ws + alloc((size_t)N * 128 * 4));  // h0 / out2 / h2
    float* buf1 = (float*)(ws + alloc((size_t)N * 256 * 4));  // g1 / g2 / y3 / h3
    float* buf2 = (float*)(ws + alloc((size_t)N * 256 * 4));  // out1 / h1
    float* a_s  = (float*)(ws + alloc((size_t)N * 2 * 4));
    float* a_d  = (float*)(ws + alloc((size_t)N * 2 * 4));
    float* ee1  = (float*)(ws + alloc((size_t)Etot * 2 * 4));
    float* ee2  = (float*)(ws + alloc((size_t)Etot * 4));
    int* offsets  = (int*)(ws + alloc((size_t)(N + 1) * 4));
    int* csr_src  = (int*)(ws + alloc((size_t)Etot * 4));
    int* csr_eid  = (int*)(ws + alloc((size_t)Etot * 4));
    int* csum     = (int*)(ws + alloc(256 * 4));
    int* coff     = (int*)(ws + alloc(256 * 4));
    float* scale  = (float*)(ws + alloc(256 * 4));
    float* shift  = (float*)(ws + alloc(256 * 4));
    size_t zone0 = off;                      // ---- zero zone start ----
    int* counts      = (int*)(ws + alloc((size_t)N * 4));
    int* cursor      = (int*)(ws + alloc((size_t)N * 4));
    unsigned* emax1  = (unsigned*)(ws + alloc((size_t)N * 2 * 4));
    unsigned* emax2  = (unsigned*)(ws + alloc((size_t)N * 4));
    double* sums0    = (double*)(ws + alloc(2 * 128 * 8));
    double* sums1    = (double*)(ws + alloc(2 * 256 * 8));
    double* sums2    = (double*)(ws + alloc(2 * 128 * 8));
    double* sums3    = (double*)(ws + alloc(2 * 64 * 8));
    size_t zone_bytes = off - zone0;

    hipMemsetAsync(ws + zone0, 0, zone_bytes, stream);

    dim3 blk(256);
    const int gM  = (N + 63) / 64;
    const int gE  = (Etot + 255) / 256;
    const int gW  = (N + 3) / 4;           // 1 wave per node, 4 waves/block
    const int nch = (N + 255) / 256;

    // ---- Phase A: h0 = relu(bn(x @ W_in + b_in)) ----
    gemm_f32<<<dim3(gM, 2), blk, 0, stream>>>(x, W_in, b_in, buf0, N, 128, 16);
    bn_stats<128><<<dim3(128), blk, 0, stream>>>(buf0, sums0, N);
    bn_fin<128><<<1, 128, 0, stream>>>(sums0, g0, be0, scale, shift, N);
    bn_apply_relu<128><<<dim3(2048), blk, 0, stream>>>(buf0, scale, shift, N * 128 / 4);

    // ---- CSR build (reused by both GAT layers) ----
    count_edges<<<gE, blk, 0, stream>>>(ei, E, N, counts);
    scan_chunk_sum<<<nch, blk, 0, stream>>>(counts, N, csum);
    scan_chunks<<<1, blk, 0, stream>>>(csum, nch, coff, offsets, N, Etot);
    scan_final<<<nch, blk, 0, stream>>>(counts, N, coff, offsets);
    scatter_edges<<<gE, blk, 0, stream>>>(ei, E, N, offsets, cursor, csr_src, csr_eid);

    // ---- Phase B: GAT layer 1 (heads=2, C=256) ----
    gemm_f32<<<dim3(gM, 4), blk, 0, stream>>>(buf0, W1, nullptr, buf1, N, 256, 128);
    att_scores<2><<<dim3(gW), blk, 0, stream>>>(buf1, as1, ad1, a_s, a_d, N);
    edge_scores<2><<<gE, blk, 0, stream>>>(ei, E, N, a_s, a_d, ee1, emax1);
    edge_exp<2><<<gE, blk, 0, stream>>>(ei, E, N, emax1, ee1);
    gat_agg<256, 2><<<dim3(gW), blk, 0, stream>>>(buf1, ee1, offsets, csr_src, csr_eid, bias1, buf2, N);
    bn_stats<256><<<dim3(128), blk, 0, stream>>>(buf2, sums1, N);
    bn_fin<256><<<1, 256, 0, stream>>>(sums1, g1, be1, scale, shift, N);
    bn_apply_relu<256><<<dim3(2048), blk, 0, stream>>>(buf2, scale, shift, N * 256 / 4);

    // ---- Phase C: GAT layer 2 (heads=1, C=128) ----
    gemm_f32<<<dim3(gM, 2), blk, 0, stream>>>(buf2, W2, nullptr, buf1, N, 128, 256);
    att_scores<1><<<dim3(gW), blk, 0, stream>>>(buf1, as2, ad2, a_s, a_d, N);
    edge_scores<1><<<gE, blk, 0, stream>>>(ei, E, N, a_s, a_d, ee2, emax2);
    edge_exp<1><<<gE, blk, 0, stream>>>(ei, E, N, emax2, ee2);
    gat_agg<128, 1><<<dim3(gW), blk, 0, stream>>>(buf1, ee2, offsets, csr_src, csr_eid, bias2, buf0, N);
    bn_stats<128><<<dim3(128), blk, 0, stream>>>(buf0, sums2, N);
    bn_fin<128><<<1, 128, 0, stream>>>(sums2, g2, be2, scale, shift, N);
    bn_apply_relu<128><<<dim3(2048), blk, 0, stream>>>(buf0, scale, shift, N * 128 / 4);

    // ---- Phase D: h3 = relu(bn(h2 @ Wf1 + bf1)) ----
    gemm_f32<<<dim3(gM, 1), blk, 0, stream>>>(buf0, Wf1, bf1, buf1, N, 64, 128);
    bn_stats<64><<<dim3(128), blk, 0, stream>>>(buf1, sums3, N);
    bn_fin<64><<<1, 64, 0, stream>>>(sums3, gf, bef, scale, shift, N);
    bn_apply_relu<64><<<dim3(2048), blk, 0, stream>>>(buf1, scale, shift, N * 64 / 4);

    // ---- Phase E: out = h3 @ Wf2 + bf2 ----
    final_dot<<<dim3(gW), blk, 0, stream>>>(buf1, Wf2, bf2, (float*)d_out, N);
}

// Round 4
// 709.648 us; speedup vs baseline: 1.4368x; 1.4368x over previous
//
#include <hip/hip_runtime.h>
#include <hip/hip_bf16.h>

// ---------------------------------------------------------------------------
// ImprovedGNN: Linear(16->128)+BN+ReLU -> GAT(2 heads,128)+BN+ReLU
//              -> GAT(1 head,128)+BN+ReLU -> Linear(128->64)+BN+ReLU -> Linear(64->1)
// GEMMs in fp32 VALU. GAT feature matrices (g1/g2) stored bf16 to halve the
// gather traffic. Attention softmax fully fused into the aggregation kernel
// (a_s/a_d are L2-resident; per-node max + exp recomputed in-kernel).
// BN stats in double. CSR built once, reused by both GAT layers.
// ---------------------------------------------------------------------------

__device__ inline float bf2f(unsigned short u) {
    return __uint_as_float(((unsigned)u) << 16);
}

// ---------------- tiled fp32 GEMM: C[M,Nc] = A[M,K] @ B[K,Nc] (+bias) ------
// BM=64, BN=64, BK=16, 256 threads, 4x4 per thread. Optional bf16 output.
template<bool BF16OUT>
__global__ __launch_bounds__(256) void gemm_f32(
    const float* __restrict__ A, const float* __restrict__ B,
    const float* __restrict__ bias, void* __restrict__ Cout,
    int M, int Nc, int K)
{
    __shared__ float As[16][68];   // [k][m]
    __shared__ float Bs[16][68];   // [k][n]
    const int t  = threadIdx.x;
    const int m0 = blockIdx.x * 64;
    const int n0 = blockIdx.y * 64;
    const int tx = t & 15;
    const int ty = t >> 4;
    const int lar = t >> 2;
    const int lac = (t & 3) * 4;
    const int lbr = t >> 4;
    const int lbc = (t & 15) * 4;

    float acc[4][4] = {};
    for (int k0 = 0; k0 < K; k0 += 16) {
        {
            int gr = m0 + lar;
            float4 v = make_float4(0.f, 0.f, 0.f, 0.f);
            if (gr < M) v = *reinterpret_cast<const float4*>(A + (size_t)gr * K + k0 + lac);
            As[lac + 0][lar] = v.x; As[lac + 1][lar] = v.y;
            As[lac + 2][lar] = v.z; As[lac + 3][lar] = v.w;
        }
        {
            float4 v = *reinterpret_cast<const float4*>(B + (size_t)(k0 + lbr) * Nc + n0 + lbc);
            *reinterpret_cast<float4*>(&Bs[lbr][lbc]) = v;
        }
        __syncthreads();
#pragma unroll
        for (int kk = 0; kk < 16; ++kk) {
            float a[4], b[4];
            *reinterpret_cast<float4*>(a) = *reinterpret_cast<const float4*>(&As[kk][ty * 4]);
            *reinterpret_cast<float4*>(b) = *reinterpret_cast<const float4*>(&Bs[kk][tx * 4]);
#pragma unroll
            for (int i = 0; i < 4; ++i)
#pragma unroll
                for (int j = 0; j < 4; ++j)
                    acc[i][j] = fmaf(a[i], b[j], acc[i][j]);
        }
        __syncthreads();
    }
    float bj[4] = {0.f, 0.f, 0.f, 0.f};
    if (bias) *reinterpret_cast<float4*>(bj) = *reinterpret_cast<const float4*>(bias + n0 + tx * 4);
#pragma unroll
    for (int i = 0; i < 4; ++i) {
        int row = m0 + ty * 4 + i;
        if (row < M) {
            float v0 = acc[i][0] + bj[0], v1 = acc[i][1] + bj[1];
            float v2 = acc[i][2] + bj[2], v3 = acc[i][3] + bj[3];
            if constexpr (BF16OUT) {
                __hip_bfloat16 h[4];
                h[0] = __float2bfloat16(v0); h[1] = __float2bfloat16(v1);
                h[2] = __float2bfloat16(v2); h[3] = __float2bfloat16(v3);
                *reinterpret_cast<uint2*>((__hip_bfloat16*)Cout + (size_t)row * Nc + n0 + tx * 4) =
                    *reinterpret_cast<uint2*>(h);
            } else {
                *reinterpret_cast<float4*>((float*)Cout + (size_t)row * Nc + n0 + tx * 4) =
                    make_float4(v0, v1, v2, v3);
            }
        }
    }
}

// ---------------- BN stats: per-column sum & sumsq in double ---------------
template<int C>
__global__ __launch_bounds__(256) void bn_stats(const float* __restrict__ y,
                                                double* __restrict__ sums, int Nn)
{
    constexpr int R = (256 / C) < 1 ? 1 : (256 / C);
    const int t = threadIdx.x;
    const int col = (C >= 256) ? t : (t % C);
    const int r0  = (C >= 256) ? 0 : (t / C);
    double s = 0.0, s2 = 0.0;
    for (int row = blockIdx.x * R + r0; row < Nn; row += gridDim.x * R) {
        float v = y[(size_t)row * C + col];
        s += v; s2 += (double)v * (double)v;
    }
    __shared__ double ls[256], ls2[256];
    ls[t] = s; ls2[t] = s2;
    __syncthreads();
    if (t < C) {
#pragma unroll
        for (int k = 1; k < R; ++k) { s += ls[t + k * C]; s2 += ls2[t + k * C]; }
        atomicAdd(&sums[col], s);
        atomicAdd(&sums[C + col], s2);
    }
}

template<int C>
__global__ void bn_fin(const double* __restrict__ sums, const float* __restrict__ g,
                       const float* __restrict__ be, float* __restrict__ sc,
                       float* __restrict__ sh, int Nn)
{
    int c = threadIdx.x;
    if (c < C) {
        double mean = sums[c] / Nn;
        double var  = sums[C + c] / Nn - mean * mean;
        if (var < 0.0) var = 0.0;
        double s = (double)g[c] / sqrt(var + 1e-5);
        sc[c] = (float)s;
        sh[c] = (float)((double)be[c] - mean * s);
    }
}

template<int C>
__global__ __launch_bounds__(256) void bn_apply_relu(float* __restrict__ y,
                                                     const float* __restrict__ sc,
                                                     const float* __restrict__ sh, int total4)
{
    int i = blockIdx.x * blockDim.x + threadIdx.x;
    int stride = gridDim.x * blockDim.x;
    for (; i < total4; i += stride) {
        float4 v = reinterpret_cast<float4*>(y)[i];
        int cb = (i * 4) % C;
        float4 s = *reinterpret_cast<const float4*>(sc + cb);
        float4 h = *reinterpret_cast<const float4*>(sh + cb);
        v.x = fmaxf(fmaf(v.x, s.x, h.x), 0.f);
        v.y = fmaxf(fmaf(v.y, s.y, h.y), 0.f);
        v.z = fmaxf(fmaf(v.z, s.z, h.z), 0.f);
        v.w = fmaxf(fmaf(v.w, s.w, h.w), 0.f);
        reinterpret_cast<float4*>(y)[i] = v;
    }
}

// ---------------- attention scores per node (bf16 features) ----------------
template<int HEADS>
__global__ __launch_bounds__(256) void att_scores(
    const __hip_bfloat16* __restrict__ g, const float* __restrict__ att_s,
    const float* __restrict__ att_d, float* __restrict__ a_s,
    float* __restrict__ a_d, int Nn)
{
    constexpr int C = HEADS * 128;
    constexpr int VEC = C / 64;
    constexpr int GROUP = 128 / VEC;   // lanes per head
    int wid  = (blockIdx.x * 256 + threadIdx.x) >> 6;
    int lane = threadIdx.x & 63;
    if (wid >= Nn) return;
    float ps = 0.f, pd = 0.f;
    const __hip_bfloat16* gp = g + (size_t)wid * C + lane * VEC;
    unsigned short u[VEC];
    if constexpr (VEC == 4) *reinterpret_cast<uint2*>(u) = *reinterpret_cast<const uint2*>(gp);
    else                    *reinterpret_cast<unsigned*>(u) = *reinterpret_cast<const unsigned*>(gp);
#pragma unroll
    for (int j = 0; j < VEC; ++j) {
        float v = bf2f(u[j]);
        ps += v * att_s[lane * VEC + j];
        pd += v * att_d[lane * VEC + j];
    }
    for (int off = 1; off < GROUP; off <<= 1) {
        ps += __shfl_xor(ps, off, 64);
        pd += __shfl_xor(pd, off, 64);
    }
    if ((lane & (GROUP - 1)) == 0) {
        int head = (lane * VEC) >> 7;
        a_s[wid * HEADS + head] = ps;
        a_d[wid * HEADS + head] = pd;
    }
}

// ---------------- CSR build -------------------------------------------------
__global__ void count_edges(const int* __restrict__ ei, int E, int Nn, int* __restrict__ counts)
{
    int k = blockIdx.x * blockDim.x + threadIdx.x;
    if (k >= E + Nn) return;
    int d = (k < E) ? ei[E + k] : (k - E);
    atomicAdd(&counts[d], 1);
}

__global__ void scan_chunk_sum(const int* __restrict__ counts, int Nn, int* __restrict__ csum)
{
    __shared__ int sh[256];
    int i = blockIdx.x * 256 + threadIdx.x;
    sh[threadIdx.x] = (i < Nn) ? counts[i] : 0;
    __syncthreads();
    for (int off = 128; off > 0; off >>= 1) {
        if (threadIdx.x < off) sh[threadIdx.x] += sh[threadIdx.x + off];
        __syncthreads();
    }
    if (threadIdx.x == 0) csum[blockIdx.x] = sh[0];
}

__global__ void scan_chunks(const int* __restrict__ csum, int nchunks, int* __restrict__ coff,
                            int* __restrict__ offsets, int Nn, int Etot)
{
    __shared__ int sh[256];
    int t = threadIdx.x;
    int v = (t < nchunks) ? csum[t] : 0;
    sh[t] = v;
    __syncthreads();
    for (int off = 1; off < 256; off <<= 1) {
        int add = (t >= off) ? sh[t - off] : 0;
        __syncthreads();
        sh[t] += add;
        __syncthreads();
    }
    if (t < nchunks) coff[t] = sh[t] - v;   // exclusive
    if (t == 0) offsets[Nn] = Etot;
}

__global__ void scan_final(const int* __restrict__ counts, int Nn,
                           const int* __restrict__ coff, int* __restrict__ offsets)
{
    __shared__ int sh[256];
    int t = threadIdx.x;
    int i = blockIdx.x * 256 + t;
    int v = (i < Nn) ? counts[i] : 0;
    sh[t] = v;
    __syncthreads();
    for (int off = 1; off < 256; off <<= 1) {
        int add = (t >= off) ? sh[t - off] : 0;
        __syncthreads();
        sh[t] += add;
        __syncthreads();
    }
    if (i < Nn) offsets[i] = coff[blockIdx.x] + sh[t] - v;
}

__global__ void scatter_edges(const int* __restrict__ ei, int E, int Nn,
                              const int* __restrict__ offsets, int* __restrict__ cursor,
                              int* __restrict__ csr_src)
{
    int k = blockIdx.x * blockDim.x + threadIdx.x;
    if (k >= E + Nn) return;
    int s, d;
    if (k < E) { s = ei[k]; d = ei[E + k]; } else { s = k - E; d = k - E; }
    int pos = offsets[d] + atomicAdd(&cursor[d], 1);
    csr_src[pos] = s;
}

// ---------------- fused GAT: per-node max + softmax + aggregation -----------
// One wave per node. Pass 1: lanes-parallel max of leaky(a_s[src]+a_d[dst]).
// Pass 2: serial over edges; all lanes share the edge; gather bf16 row.
template<int C, int HEADS>
__global__ __launch_bounds__(256) void gat_agg_fused(
    const __hip_bfloat16* __restrict__ hfeat,
    const float* __restrict__ a_s, const float* __restrict__ a_d,
    const int* __restrict__ offsets, const int* __restrict__ csr_src,
    const float* __restrict__ bias, float* __restrict__ out, int Nn)
{
    constexpr int VEC = C / 64;                 // bf16 elements per lane
    int wid  = (blockIdx.x * 256 + threadIdx.x) >> 6;
    int lane = threadIdx.x & 63;
    if (wid >= Nn) return;
    const int head = (HEADS == 1) ? 0 : (lane >> 5);   // lane*VEC/128
    const int beg = offsets[wid], end = offsets[wid + 1];

    float ad0 = a_d[wid * HEADS + 0];
    float ad1 = (HEADS == 2) ? a_d[wid * HEADS + 1] : 0.f;
    const float adh = (head == 0) ? ad0 : ad1;

    // ---- pass 1: per-head running max (lanes parallel over edges) ----
    float m0 = -1e30f, m1 = -1e30f;
    for (int p = beg + lane; p < end; p += 64) {
        int s = csr_src[p];
        {
            float e = a_s[s * HEADS + 0] + ad0;
            e = (e > 0.f) ? e : 0.2f * e;
            m0 = fmaxf(m0, e);
        }
        if (HEADS == 2) {
            float e = a_s[s * HEADS + 1] + ad1;
            e = (e > 0.f) ? e : 0.2f * e;
            m1 = fmaxf(m1, e);
        }
    }
    for (int off = 1; off < 64; off <<= 1) {
        m0 = fmaxf(m0, __shfl_xor(m0, off, 64));
        if (HEADS == 2) m1 = fmaxf(m1, __shfl_xor(m1, off, 64));
    }
    const float mh = (head == 0) ? m0 : m1;

    // ---- pass 2: gather + weighted accumulate ----
    float acc[VEC] = {};
    float wsum = 0.f;
    for (int p = beg; p < end; ++p) {
        int s = csr_src[p];
        float e = a_s[s * HEADS + head] + adh;
        e = (e > 0.f) ? e : 0.2f * e;
        float w = expf(e - mh);
        wsum += w;
        const __hip_bfloat16* hp = hfeat + (size_t)s * C + lane * VEC;
        if constexpr (VEC == 4) {
            uint2 d = *reinterpret_cast<const uint2*>(hp);
            acc[0] = fmaf(w, bf2f((unsigned short)(d.x & 0xffff)), acc[0]);
            acc[1] = fmaf(w, bf2f((unsigned short)(d.x >> 16)),    acc[1]);
            acc[2] = fmaf(w, bf2f((unsigned short)(d.y & 0xffff)), acc[2]);
            acc[3] = fmaf(w, bf2f((unsigned short)(d.y >> 16)),    acc[3]);
        } else {
            unsigned d = *reinterpret_cast<const unsigned*>(hp);
            acc[0] = fmaf(w, bf2f((unsigned short)(d & 0xffff)), acc[0]);
            acc[1] = fmaf(w, bf2f((unsigned short)(d >> 16)),    acc[1]);
        }
    }
    float inv = 1.f / (wsum + 1e-16f);
    float* op = out + (size_t)wid * C + lane * VEC;
    if constexpr (VEC == 4) {
        *reinterpret_cast<float4*>(op) = make_float4(
            fmaf(acc[0], inv, bias[lane * 4 + 0]), fmaf(acc[1], inv, bias[lane * 4 + 1]),
            fmaf(acc[2], inv, bias[lane * 4 + 2]), fmaf(acc[3], inv, bias[lane * 4 + 3]));
    } else {
        *reinterpret_cast<float2*>(op) = make_float2(
            fmaf(acc[0], inv, bias[lane * 2 + 0]), fmaf(acc[1], inv, bias[lane * 2 + 1]));
    }
}

// ---------------- final dot (N,64)@(64,1) -----------------------------------
__global__ __launch_bounds__(256) void final_dot(const float* __restrict__ h3,
                                                 const float* __restrict__ w,
                                                 const float* __restrict__ b,
                                                 float* __restrict__ out, int Nn)
{
    int wid  = (blockIdx.x * 256 + threadIdx.x) >> 6;
    int lane = threadIdx.x & 63;
    if (wid >= Nn) return;
    float v = h3[(size_t)wid * 64 + lane] * w[lane];
    for (int off = 32; off > 0; off >>= 1) v += __shfl_xor(v, off, 64);
    if (lane == 0) out[wid] = v + b[0];
}

// ---------------------------------------------------------------------------
extern "C" void kernel_launch(void* const* d_in, const int* in_sizes, int n_in,
                              void* d_out, int out_size, void* d_ws, size_t ws_size,
                              hipStream_t stream)
{
    const float* x     = (const float*)d_in[0];
    const int*   ei    = (const int*)d_in[1];
    const float* W_in  = (const float*)d_in[2];
    const float* b_in  = (const float*)d_in[3];
    const float* g0    = (const float*)d_in[4];
    const float* be0   = (const float*)d_in[5];
    const float* W1    = (const float*)d_in[6];
    const float* as1   = (const float*)d_in[7];
    const float* ad1   = (const float*)d_in[8];
    const float* bias1 = (const float*)d_in[9];
    const float* g1    = (const float*)d_in[10];
    const float* be1   = (const float*)d_in[11];
    const float* W2    = (const float*)d_in[12];
    const float* as2   = (const float*)d_in[13];
    const float* ad2   = (const float*)d_in[14];
    const float* bias2 = (const float*)d_in[15];
    const float* g2    = (const float*)d_in[16];
    const float* be2   = (const float*)d_in[17];
    const float* Wf1   = (const float*)d_in[18];
    const float* bf1   = (const float*)d_in[19];
    const float* gf    = (const float*)d_in[20];
    const float* bef   = (const float*)d_in[21];
    const float* Wf2   = (const float*)d_in[22];
    const float* bf2   = (const float*)d_in[23];

    const int N    = in_sizes[0] / 16;     // 50000
    const int E    = in_sizes[1] / 2;      // 800000
    const int Etot = E + N;

    // ---- workspace layout ----
    char* ws = (char*)d_ws;
    size_t off = 0;
    auto alloc = [&](size_t bytes) {
        size_t o = off;
        off += (bytes + 255) & ~(size_t)255;
        return o;
    };
    float* buf0 = (float*)(ws + alloc((size_t)N * 128 * 4));          // h0 / out2 / h2
    float* buf2 = (float*)(ws + alloc((size_t)N * 256 * 4));          // out1 / h1
    float* buf1 = (float*)(ws + alloc((size_t)N * 64 * 4));           // y3 / h3
    __hip_bfloat16* gbuf = (__hip_bfloat16*)(ws + alloc((size_t)N * 256 * 2)); // g1 / g2 (bf16)
    float* a_s  = (float*)(ws + alloc((size_t)N * 2 * 4));
    float* a_d  = (float*)(ws + alloc((size_t)N * 2 * 4));
    int* offsets  = (int*)(ws + alloc((size_t)(N + 1) * 4));
    int* csr_src  = (int*)(ws + alloc((size_t)Etot * 4));
    int* csum     = (int*)(ws + alloc(256 * 4));
    int* coff     = (int*)(ws + alloc(256 * 4));
    float* scale  = (float*)(ws + alloc(256 * 4));
    float* shift  = (float*)(ws + alloc(256 * 4));
    size_t zone0 = off;                      // ---- zero zone start ----
    int* counts      = (int*)(ws + alloc((size_t)N * 4));
    int* cursor      = (int*)(ws + alloc((size_t)N * 4));
    double* sums0    = (double*)(ws + alloc(2 * 128 * 8));
    double* sums1    = (double*)(ws + alloc(2 * 256 * 8));
    double* sums2    = (double*)(ws + alloc(2 * 128 * 8));
    double* sums3    = (double*)(ws + alloc(2 * 64 * 8));
    size_t zone_bytes = off - zone0;

    hipMemsetAsync(ws + zone0, 0, zone_bytes, stream);

    dim3 blk(256);
    const int gM  = (N + 63) / 64;
    const int gE  = (Etot + 255) / 256;
    const int gW  = (N + 3) / 4;           // 1 wave per node
    const int nch = (N + 255) / 256;

    // ---- Phase A: h0 = relu(bn(x @ W_in + b_in)) ----
    gemm_f32<false><<<dim3(gM, 2), blk, 0, stream>>>(x, W_in, b_in, buf0, N, 128, 16);
    bn_stats<128><<<dim3(400), blk, 0, stream>>>(buf0, sums0, N);
    bn_fin<128><<<1, 128, 0, stream>>>(sums0, g0, be0, scale, shift, N);
    bn_apply_relu<128><<<dim3(2048), blk, 0, stream>>>(buf0, scale, shift, N * 128 / 4);

    // ---- CSR build (reused by both GAT layers) ----
    count_edges<<<gE, blk, 0, stream>>>(ei, E, N, counts);
    scan_chunk_sum<<<nch, blk, 0, stream>>>(counts, N, csum);
    scan_chunks<<<1, blk, 0, stream>>>(csum, nch, coff, offsets, N, Etot);
    scan_final<<<nch, blk, 0, stream>>>(counts, N, coff, offsets);
    scatter_edges<<<gE, blk, 0, stream>>>(ei, E, N, offsets, cursor, csr_src);

    // ---- Phase B: GAT layer 1 (heads=2, C=256) ----
    gemm_f32<true><<<dim3(gM, 4), blk, 0, stream>>>(buf0, W1, nullptr, gbuf, N, 256, 128);
    att_scores<2><<<dim3(gW), blk, 0, stream>>>(gbuf, as1, ad1, a_s, a_d, N);
    gat_agg_fused<256, 2><<<dim3(gW), blk, 0, stream>>>(gbuf, a_s, a_d, offsets, csr_src, bias1, buf2, N);
    bn_stats<256><<<dim3(400), blk, 0, stream>>>(buf2, sums1, N);
    bn_fin<256><<<1, 256, 0, stream>>>(sums1, g1, be1, scale, shift, N);
    bn_apply_relu<256><<<dim3(2048), blk, 0, stream>>>(buf2, scale, shift, N * 256 / 4);

    // ---- Phase C: GAT layer 2 (heads=1, C=128) ----
    gemm_f32<true><<<dim3(gM, 2), blk, 0, stream>>>(buf2, W2, nullptr, gbuf, N, 128, 256);
    att_scores<1><<<dim3(gW), blk, 0, stream>>>(gbuf, as2, ad2, a_s, a_d, N);
    gat_agg_fused<128, 1><<<dim3(gW), blk, 0, stream>>>(gbuf, a_s, a_d, offsets, csr_src, bias2, buf0, N);
    bn_stats<128><<<dim3(400), blk, 0, stream>>>(buf0, sums2, N);
    bn_fin<128><<<1, 128, 0, stream>>>(sums2, g2, be2, scale, shift, N);
    bn_apply_relu<128><<<dim3(2048), blk, 0, stream>>>(buf0, scale, shift, N * 128 / 4);

    // ---- Phase D: h3 = relu(bn(h2 @ Wf1 + bf1)) ----
    gemm_f32<false><<<dim3(gM, 1), blk, 0, stream>>>(buf0, Wf1, bf1, buf1, N, 64, 128);
    bn_stats<64><<<dim3(400), blk, 0, stream>>>(buf1, sums3, N);
    bn_fin<64><<<1, 64, 0, stream>>>(sums3, gf, bef, scale, shift, N);
    bn_apply_relu<64><<<dim3(2048), blk, 0, stream>>>(buf1, scale, shift, N * 64 / 4);

    // ---- Phase E: out = h3 @ Wf2 + bf2 ----
    final_dot<<<dim3(gW), blk, 0, stream>>>(buf1, Wf2, bf2, (float*)d_out, N);
}

// Round 8
// 622.458 us; speedup vs baseline: 1.6380x; 1.1401x over previous
//
#include <hip/hip_runtime.h>
#include <hip/hip_bf16.h>

// ---------------------------------------------------------------------------
// ImprovedGNN: Linear(16->128)+BN+ReLU -> GAT(2 heads,128)+BN+ReLU
//              -> GAT(1 head,128)+BN+ReLU -> Linear(128->64)+BN+ReLU -> Linear(64->1)
// GEMMs in fp32 VALU. GAT feature matrices bf16 (halves gather traffic).
// Softmax fused into aggregation; pass 2 processes 4 edges in parallel via
// 16-lane groups (R4: serial one-edge-per-wave loop was issue/latency-bound:
// 27% HBM, 51% VALUBusy at 115us).
// BN stats in double. CSR built once, reused by both GAT layers.
// ---------------------------------------------------------------------------

__device__ inline float bf2f(unsigned short u) {
    return __uint_as_float(((unsigned)u) << 16);
}

// ---------------- tiled fp32 GEMM: C[M,Nc] = A[M,K] @ B[K,Nc] (+bias) ------
template<bool BF16OUT>
__global__ __launch_bounds__(256) void gemm_f32(
    const float* __restrict__ A, const float* __restrict__ B,
    const float* __restrict__ bias, void* __restrict__ Cout,
    int M, int Nc, int K)
{
    __shared__ float As[16][68];   // [k][m]
    __shared__ float Bs[16][68];   // [k][n]
    const int t  = threadIdx.x;
    const int m0 = blockIdx.x * 64;
    const int n0 = blockIdx.y * 64;
    const int tx = t & 15;
    const int ty = t >> 4;
    const int lar = t >> 2;
    const int lac = (t & 3) * 4;
    const int lbr = t >> 4;
    const int lbc = (t & 15) * 4;

    float acc[4][4] = {};
    for (int k0 = 0; k0 < K; k0 += 16) {
        {
            int gr = m0 + lar;
            float4 v = make_float4(0.f, 0.f, 0.f, 0.f);
            if (gr < M) v = *reinterpret_cast<const float4*>(A + (size_t)gr * K + k0 + lac);
            As[lac + 0][lar] = v.x; As[lac + 1][lar] = v.y;
            As[lac + 2][lar] = v.z; As[lac + 3][lar] = v.w;
        }
        {
            float4 v = *reinterpret_cast<const float4*>(B + (size_t)(k0 + lbr) * Nc + n0 + lbc);
            *reinterpret_cast<float4*>(&Bs[lbr][lbc]) = v;
        }
        __syncthreads();
#pragma unroll
        for (int kk = 0; kk < 16; ++kk) {
            float a[4], b[4];
            *reinterpret_cast<float4*>(a) = *reinterpret_cast<const float4*>(&As[kk][ty * 4]);
            *reinterpret_cast<float4*>(b) = *reinterpret_cast<const float4*>(&Bs[kk][tx * 4]);
#pragma unroll
            for (int i = 0; i < 4; ++i)
#pragma unroll
                for (int j = 0; j < 4; ++j)
                    acc[i][j] = fmaf(a[i], b[j], acc[i][j]);
        }
        __syncthreads();
    }
    float bj[4] = {0.f, 0.f, 0.f, 0.f};
    if (bias) *reinterpret_cast<float4*>(bj) = *reinterpret_cast<const float4*>(bias + n0 + tx * 4);
#pragma unroll
    for (int i = 0; i < 4; ++i) {
        int row = m0 + ty * 4 + i;
        if (row < M) {
            float v0 = acc[i][0] + bj[0], v1 = acc[i][1] + bj[1];
            float v2 = acc[i][2] + bj[2], v3 = acc[i][3] + bj[3];
            if constexpr (BF16OUT) {
                __hip_bfloat16 h[4];
                h[0] = __float2bfloat16(v0); h[1] = __float2bfloat16(v1);
                h[2] = __float2bfloat16(v2); h[3] = __float2bfloat16(v3);
                *reinterpret_cast<uint2*>((__hip_bfloat16*)Cout + (size_t)row * Nc + n0 + tx * 4) =
                    *reinterpret_cast<uint2*>(h);
            } else {
                *reinterpret_cast<float4*>((float*)Cout + (size_t)row * Nc + n0 + tx * 4) =
                    make_float4(v0, v1, v2, v3);
            }
        }
    }
}

// ---------------- BN stats: per-column sum & sumsq in double ---------------
template<int C>
__global__ __launch_bounds__(256) void bn_stats(const float* __restrict__ y,
                                                double* __restrict__ sums, int Nn)
{
    constexpr int R = (256 / C) < 1 ? 1 : (256 / C);
    const int t = threadIdx.x;
    const int col = (C >= 256) ? t : (t % C);
    const int r0  = (C >= 256) ? 0 : (t / C);
    double s = 0.0, s2 = 0.0;
    for (int row = blockIdx.x * R + r0; row < Nn; row += gridDim.x * R) {
        float v = y[(size_t)row * C + col];
        s += v; s2 += (double)v * (double)v;
    }
    __shared__ double ls[256], ls2[256];
    ls[t] = s; ls2[t] = s2;
    __syncthreads();
    if (t < C) {
#pragma unroll
        for (int k = 1; k < R; ++k) { s += ls[t + k * C]; s2 += ls2[t + k * C]; }
        atomicAdd(&sums[col], s);
        atomicAdd(&sums[C + col], s2);
    }
}

template<int C>
__global__ void bn_fin(const double* __restrict__ sums, const float* __restrict__ g,
                       const float* __restrict__ be, float* __restrict__ sc,
                       float* __restrict__ sh, int Nn)
{
    int c = threadIdx.x;
    if (c < C) {
        double mean = sums[c] / Nn;
        double var  = sums[C + c] / Nn - mean * mean;
        if (var < 0.0) var = 0.0;
        double s = (double)g[c] / sqrt(var + 1e-5);
        sc[c] = (float)s;
        sh[c] = (float)((double)be[c] - mean * s);
    }
}

template<int C>
__global__ __launch_bounds__(256) void bn_apply_relu(float* __restrict__ y,
                                                     const float* __restrict__ sc,
                                                     const float* __restrict__ sh, int total4)
{
    int i = blockIdx.x * blockDim.x + threadIdx.x;
    int stride = gridDim.x * blockDim.x;
    for (; i < total4; i += stride) {
        float4 v = reinterpret_cast<float4*>(y)[i];
        int cb = (i * 4) % C;
        float4 s = *reinterpret_cast<const float4*>(sc + cb);
        float4 h = *reinterpret_cast<const float4*>(sh + cb);
        v.x = fmaxf(fmaf(v.x, s.x, h.x), 0.f);
        v.y = fmaxf(fmaf(v.y, s.y, h.y), 0.f);
        v.z = fmaxf(fmaf(v.z, s.z, h.z), 0.f);
        v.w = fmaxf(fmaf(v.w, s.w, h.w), 0.f);
        reinterpret_cast<float4*>(y)[i] = v;
    }
}

// ---------------- attention scores per node (bf16 features) ----------------
template<int HEADS>
__global__ __launch_bounds__(256) void att_scores(
    const __hip_bfloat16* __restrict__ g, const float* __restrict__ att_s,
    const float* __restrict__ att_d, float* __restrict__ a_s,
    float* __restrict__ a_d, int Nn)
{
    constexpr int C = HEADS * 128;
    constexpr int VEC = C / 64;
    constexpr int GROUP = 128 / VEC;   // lanes per head
    int wid  = (blockIdx.x * 256 + threadIdx.x) >> 6;
    int lane = threadIdx.x & 63;
    if (wid >= Nn) return;
    float ps = 0.f, pd = 0.f;
    const __hip_bfloat16* gp = g + (size_t)wid * C + lane * VEC;
    unsigned short u[VEC];
    if constexpr (VEC == 4) *reinterpret_cast<uint2*>(u) = *reinterpret_cast<const uint2*>(gp);
    else                    *reinterpret_cast<unsigned*>(u) = *reinterpret_cast<const unsigned*>(gp);
#pragma unroll
    for (int j = 0; j < VEC; ++j) {
        float v = bf2f(u[j]);
        ps += v * att_s[lane * VEC + j];
        pd += v * att_d[lane * VEC + j];
    }
    for (int off = 1; off < GROUP; off <<= 1) {
        ps += __shfl_xor(ps, off, 64);
        pd += __shfl_xor(pd, off, 64);
    }
    if ((lane & (GROUP - 1)) == 0) {
        int head = (lane * VEC) >> 7;
        a_s[wid * HEADS + head] = ps;
        a_d[wid * HEADS + head] = pd;
    }
}

// ---------------- CSR build -------------------------------------------------
__global__ void count_edges(const int* __restrict__ ei, int E, int Nn, int* __restrict__ counts)
{
    int k = blockIdx.x * blockDim.x + threadIdx.x;
    if (k >= E + Nn) return;
    int d = (k < E) ? ei[E + k] : (k - E);
    atomicAdd(&counts[d], 1);
}

__global__ void scan_chunk_sum(const int* __restrict__ counts, int Nn, int* __restrict__ csum)
{
    __shared__ int sh[256];
    int i = blockIdx.x * 256 + threadIdx.x;
    sh[threadIdx.x] = (i < Nn) ? counts[i] : 0;
    __syncthreads();
    for (int off = 128; off > 0; off >>= 1) {
        if (threadIdx.x < off) sh[threadIdx.x] += sh[threadIdx.x + off];
        __syncthreads();
    }
    if (threadIdx.x == 0) csum[blockIdx.x] = sh[0];
}

__global__ void scan_chunks(const int* __restrict__ csum, int nchunks, int* __restrict__ coff,
                            int* __restrict__ offsets, int Nn, int Etot)
{
    __shared__ int sh[256];
    int t = threadIdx.x;
    int v = (t < nchunks) ? csum[t] : 0;
    sh[t] = v;
    __syncthreads();
    for (int off = 1; off < 256; off <<= 1) {
        int add = (t >= off) ? sh[t - off] : 0;
        __syncthreads();
        sh[t] += add;
        __syncthreads();
    }
    if (t < nchunks) coff[t] = sh[t] - v;   // exclusive
    if (t == 0) offsets[Nn] = Etot;
}

__global__ void scan_final(const int* __restrict__ counts, int Nn,
                           const int* __restrict__ coff, int* __restrict__ offsets)
{
    __shared__ int sh[256];
    int t = threadIdx.x;
    int i = blockIdx.x * 256 + t;
    int v = (i < Nn) ? counts[i] : 0;
    sh[t] = v;
    __syncthreads();
    for (int off = 1; off < 256; off <<= 1) {
        int add = (t >= off) ? sh[t - off] : 0;
        __syncthreads();
        sh[t] += add;
        __syncthreads();
    }
    if (i < Nn) offsets[i] = coff[blockIdx.x] + sh[t] - v;
}

__global__ void scatter_edges(const int* __restrict__ ei, int E, int Nn,
                              const int* __restrict__ offsets, int* __restrict__ cursor,
                              int* __restrict__ csr_src)
{
    int k = blockIdx.x * blockDim.x + threadIdx.x;
    if (k >= E + Nn) return;
    int s, d;
    if (k < E) { s = ei[k]; d = ei[E + k]; } else { s = k - E; d = k - E; }
    int pos = offsets[d] + atomicAdd(&cursor[d], 1);
    csr_src[pos] = s;
}

// ---------------- fused GAT: per-node max + softmax + aggregation -----------
// One wave per node. Pass 1: lanes-parallel max of leaky(a_s[src]+a_d[dst]).
// Pass 2: FOUR edges in parallel, one per 16-lane group. Each lane reads 16B
// (8 bf16) of each 128-dim head-chunk => contiguous 256B per group per chunk.
// Cross-group butterfly reduce (xor 16,32) combines partial sums.
template<int C, int HEADS>
__global__ __launch_bounds__(256) void gat_agg_fused(
    const __hip_bfloat16* __restrict__ hfeat,
    const float* __restrict__ a_s, const float* __restrict__ a_d,
    const int* __restrict__ offsets, const int* __restrict__ csr_src,
    const float* __restrict__ bias, float* __restrict__ out, int Nn)
{
    int wid  = (blockIdx.x * 256 + threadIdx.x) >> 6;
    int lane = threadIdx.x & 63;
    if (wid >= Nn) return;
    const int gid = lane >> 4;         // edge group 0..3
    const int gl  = lane & 15;         // lane within group
    const int beg = offsets[wid], end = offsets[wid + 1];

    float ad[HEADS];
#pragma unroll
    for (int h = 0; h < HEADS; ++h) ad[h] = a_d[wid * HEADS + h];

    // ---- pass 1: per-head running max (all 64 lanes parallel over edges) ----
    float m[HEADS];
#pragma unroll
    for (int h = 0; h < HEADS; ++h) m[h] = -1e30f;
    for (int p = beg + lane; p < end; p += 64) {
        int s = csr_src[p];
#pragma unroll
        for (int h = 0; h < HEADS; ++h) {
            float e = a_s[s * HEADS + h] + ad[h];
            e = (e > 0.f) ? e : 0.2f * e;
            m[h] = fmaxf(m[h], e);
        }
    }
    for (int off = 1; off < 64; off <<= 1) {
#pragma unroll
        for (int h = 0; h < HEADS; ++h) m[h] = fmaxf(m[h], __shfl_xor(m[h], off, 64));
    }

    // ---- pass 2: gather + weighted accumulate, 4 edges at a time ----
    float acc[HEADS][8];
#pragma unroll
    for (int h = 0; h < HEADS; ++h)
#pragma unroll
        for (int j = 0; j < 8; ++j) acc[h][j] = 0.f;
    float wsum[HEADS];
#pragma unroll
    for (int h = 0; h < HEADS; ++h) wsum[h] = 0.f;

    for (int p0 = beg; p0 < end; p0 += 4) {
        int p = p0 + gid;
        bool act = (p < end);
        int s = csr_src[act ? p : beg];
        float w[HEADS];
#pragma unroll
        for (int h = 0; h < HEADS; ++h) {
            float e = a_s[s * HEADS + h] + ad[h];
            e = (e > 0.f) ? e : 0.2f * e;
            w[h] = act ? __expf(e - m[h]) : 0.f;
            wsum[h] += w[h];
        }
        if (act) {
            const __hip_bfloat16* row = hfeat + (size_t)s * C;
#pragma unroll
            for (int h = 0; h < HEADS; ++h) {
                uint4 d = *reinterpret_cast<const uint4*>(row + h * 128 + gl * 8);
                float wh = w[h];
                acc[h][0] = fmaf(wh, bf2f((unsigned short)(d.x & 0xffff)), acc[h][0]);
                acc[h][1] = fmaf(wh, bf2f((unsigned short)(d.x >> 16)),    acc[h][1]);
                acc[h][2] = fmaf(wh, bf2f((unsigned short)(d.y & 0xffff)), acc[h][2]);
                acc[h][3] = fmaf(wh, bf2f((unsigned short)(d.y >> 16)),    acc[h][3]);
                acc[h][4] = fmaf(wh, bf2f((unsigned short)(d.z & 0xffff)), acc[h][4]);
                acc[h][5] = fmaf(wh, bf2f((unsigned short)(d.z >> 16)),    acc[h][5]);
                acc[h][6] = fmaf(wh, bf2f((unsigned short)(d.w & 0xffff)), acc[h][6]);
                acc[h][7] = fmaf(wh, bf2f((unsigned short)(d.w >> 16)),    acc[h][7]);
            }
        }
    }

    // ---- cross-group butterfly reduce (xor 16, 32) ----
#pragma unroll
    for (int off = 16; off < 64; off <<= 1) {
#pragma unroll
        for (int h = 0; h < HEADS; ++h) {
            wsum[h] += __shfl_xor(wsum[h], off, 64);
#pragma unroll
            for (int j = 0; j < 8; ++j) acc[h][j] += __shfl_xor(acc[h][j], off, 64);
        }
    }

    // ---- write (group 0 only; lanes 0..15 cover the row) ----
    if (gid == 0) {
        float* op = out + (size_t)wid * C;
#pragma unroll
        for (int h = 0; h < HEADS; ++h) {
            float inv = 1.f / (wsum[h] + 1e-16f);
            const float* bp = bias + h * 128 + gl * 8;
            float4 v0 = make_float4(
                fmaf(acc[h][0], inv, bp[0]), fmaf(acc[h][1], inv, bp[1]),
                fmaf(acc[h][2], inv, bp[2]), fmaf(acc[h][3], inv, bp[3]));
            float4 v1 = make_float4(
                fmaf(acc[h][4], inv, bp[4]), fmaf(acc[h][5], inv, bp[5]),
                fmaf(acc[h][6], inv, bp[6]), fmaf(acc[h][7], inv, bp[7]));
            *reinterpret_cast<float4*>(op + h * 128 + gl * 8)     = v0;
            *reinterpret_cast<float4*>(op + h * 128 + gl * 8 + 4) = v1;
        }
    }
}

// ---------------- final dot (N,64)@(64,1) -----------------------------------
__global__ __launch_bounds__(256) void final_dot(const float* __restrict__ h3,
                                                 const float* __restrict__ w,
                                                 const float* __restrict__ b,
                                                 float* __restrict__ out, int Nn)
{
    int wid  = (blockIdx.x * 256 + threadIdx.x) >> 6;
    int lane = threadIdx.x & 63;
    if (wid >= Nn) return;
    float v = h3[(size_t)wid * 64 + lane] * w[lane];
    for (int off = 32; off > 0; off >>= 1) v += __shfl_xor(v, off, 64);
    if (lane == 0) out[wid] = v + b[0];
}

// ---------------------------------------------------------------------------
extern "C" void kernel_launch(void* const* d_in, const int* in_sizes, int n_in,
                              void* d_out, int out_size, void* d_ws, size_t ws_size,
                              hipStream_t stream)
{
    const float* x     = (const float*)d_in[0];
    const int*   ei    = (const int*)d_in[1];
    const float* W_in  = (const float*)d_in[2];
    const float* b_in  = (const float*)d_in[3];
    const float* g0    = (const float*)d_in[4];
    const float* be0   = (const float*)d_in[5];
    const float* W1    = (const float*)d_in[6];
    const float* as1   = (const float*)d_in[7];
    const float* ad1   = (const float*)d_in[8];
    const float* bias1 = (const float*)d_in[9];
    const float* g1    = (const float*)d_in[10];
    const float* be1   = (const float*)d_in[11];
    const float* W2    = (const float*)d_in[12];
    const float* as2   = (const float*)d_in[13];
    const float* ad2   = (const float*)d_in[14];
    const float* bias2 = (const float*)d_in[15];
    const float* g2    = (const float*)d_in[16];
    const float* be2   = (const float*)d_in[17];
    const float* Wf1   = (const float*)d_in[18];
    const float* bf1   = (const float*)d_in[19];
    const float* gf    = (const float*)d_in[20];
    const float* bef   = (const float*)d_in[21];
    const float* Wf2   = (const float*)d_in[22];
    const float* bf2   = (const float*)d_in[23];

    const int N    = in_sizes[0] / 16;     // 50000
    const int E    = in_sizes[1] / 2;      // 800000
    const int Etot = E + N;

    // ---- workspace layout ----
    char* ws = (char*)d_ws;
    size_t off = 0;
    auto alloc = [&](size_t bytes) {
        size_t o = off;
        off += (bytes + 255) & ~(size_t)255;
        return o;
    };
    float* buf0 = (float*)(ws + alloc((size_t)N * 128 * 4));          // h0 / out2 / h2
    float* buf2 = (float*)(ws + alloc((size_t)N * 256 * 4));          // out1 / h1
    float* buf1 = (float*)(ws + alloc((size_t)N * 64 * 4));           // y3 / h3
    __hip_bfloat16* gbuf = (__hip_bfloat16*)(ws + alloc((size_t)N * 256 * 2)); // g1 / g2 (bf16)
    float* a_s  = (float*)(ws + alloc((size_t)N * 2 * 4));
    float* a_d  = (float*)(ws + alloc((size_t)N * 2 * 4));
    int* offsets  = (int*)(ws + alloc((size_t)(N + 1) * 4));
    int* csr_src  = (int*)(ws + alloc((size_t)Etot * 4));
    int* csum     = (int*)(ws + alloc(256 * 4));
    int* coff     = (int*)(ws + alloc(256 * 4));
    float* scale  = (float*)(ws + alloc(256 * 4));
    float* shift  = (float*)(ws + alloc(256 * 4));
    size_t zone0 = off;                      // ---- zero zone start ----
    int* counts      = (int*)(ws + alloc((size_t)N * 4));
    int* cursor      = (int*)(ws + alloc((size_t)N * 4));
    double* sums0    = (double*)(ws + alloc(2 * 128 * 8));
    double* sums1    = (double*)(ws + alloc(2 * 256 * 8));
    double* sums2    = (double*)(ws + alloc(2 * 128 * 8));
    double* sums3    = (double*)(ws + alloc(2 * 64 * 8));
    size_t zone_bytes = off - zone0;

    hipMemsetAsync(ws + zone0, 0, zone_bytes, stream);

    dim3 blk(256);
    const int gM  = (N + 63) / 64;
    const int gE  = (Etot + 255) / 256;
    const int gW  = (N + 3) / 4;           // 1 wave per node
    const int nch = (N + 255) / 256;

    // ---- Phase A: h0 = relu(bn(x @ W_in + b_in)) ----
    gemm_f32<false><<<dim3(gM, 2), blk, 0, stream>>>(x, W_in, b_in, buf0, N, 128, 16);
    bn_stats<128><<<dim3(400), blk, 0, stream>>>(buf0, sums0, N);
    bn_fin<128><<<1, 128, 0, stream>>>(sums0, g0, be0, scale, shift, N);
    bn_apply_relu<128><<<dim3(2048), blk, 0, stream>>>(buf0, scale, shift, N * 128 / 4);

    // ---- CSR build (reused by both GAT layers) ----
    count_edges<<<gE, blk, 0, stream>>>(ei, E, N, counts);
    scan_chunk_sum<<<nch, blk, 0, stream>>>(counts, N, csum);
    scan_chunks<<<1, blk, 0, stream>>>(csum, nch, coff, offsets, N, Etot);
    scan_final<<<nch, blk, 0, stream>>>(counts, N, coff, offsets);
    scatter_edges<<<gE, blk, 0, stream>>>(ei, E, N, offsets, cursor, csr_src);

    // ---- Phase B: GAT layer 1 (heads=2, C=256) ----
    gemm_f32<true><<<dim3(gM, 4), blk, 0, stream>>>(buf0, W1, nullptr, gbuf, N, 256, 128);
    att_scores<2><<<dim3(gW), blk, 0, stream>>>(gbuf, as1, ad1, a_s, a_d, N);
    gat_agg_fused<256, 2><<<dim3(gW), blk, 0, stream>>>(gbuf, a_s, a_d, offsets, csr_src, bias1, buf2, N);
    bn_stats<256><<<dim3(400), blk, 0, stream>>>(buf2, sums1, N);
    bn_fin<256><<<1, 256, 0, stream>>>(sums1, g1, be1, scale, shift, N);
    bn_apply_relu<256><<<dim3(2048), blk, 0, stream>>>(buf2, scale, shift, N * 256 / 4);

    // ---- Phase C: GAT layer 2 (heads=1, C=128) ----
    gemm_f32<true><<<dim3(gM, 2), blk, 0, stream>>>(buf2, W2, nullptr, gbuf, N, 128, 256);
    att_scores<1><<<dim3(gW), blk, 0, stream>>>(gbuf, as2, ad2, a_s, a_d, N);
    gat_agg_fused<128, 1><<<dim3(gW), blk, 0, stream>>>(gbuf, a_s, a_d, offsets, csr_src, bias2, buf0, N);
    bn_stats<128><<<dim3(400), blk, 0, stream>>>(buf0, sums2, N);
    bn_fin<128><<<1, 128, 0, stream>>>(sums2, g2, be2, scale, shift, N);
    bn_apply_relu<128><<<dim3(2048), blk, 0, stream>>>(buf0, scale, shift, N * 128 / 4);

    // ---- Phase D: h3 = relu(bn(h2 @ Wf1 + bf1)) ----
    gemm_f32<false><<<dim3(gM, 1), blk, 0, stream>>>(buf0, Wf1, bf1, buf1, N, 64, 128);
    bn_stats<64><<<dim3(400), blk, 0, stream>>>(buf1, sums3, N);
    bn_fin<64><<<1, 64, 0, stream>>>(sums3, gf, bef, scale, shift, N);
    bn_apply_relu<64><<<dim3(2048), blk, 0, stream>>>(buf1, scale, shift, N * 64 / 4);

    // ---- Phase E: out = h3 @ Wf2 + bf2 ----
    final_dot<<<dim3(gW), blk, 0, stream>>>(buf1, Wf2, bf2, (float*)d_out, N);
}

// Round 16
// 595.161 us; speedup vs baseline: 1.7131x; 1.0459x over previous
//
#include <hip/hip_runtime.h>
#include <hip/hip_bf16.h>

// ---------------------------------------------------------------------------
// ImprovedGNN: Linear(16->128)+BN+ReLU -> GAT(2 heads,128)+BN+ReLU
//              -> GAT(1 head,128)+BN+ReLU -> Linear(128->64)+BN+ReLU -> Linear(64->1)
// R9: the three big GEMMs (W1,W2,Wf1) moved to MFMA with split-bf16 (hi+lo)
// 3-term products => fp32-class accuracy at matrix-core speed. Fragment
// packing fused into the BN+ReLU pass (bn_apply_frag); weights pre-packed.
// gat_agg: 4-edge-parallel 16-lane groups (R8: 81.5us, 38% HBM).
// BN stats in double. CSR built once. ws_size guard -> legacy VALU path.
// ---------------------------------------------------------------------------

typedef short bf16x8 __attribute__((ext_vector_type(8)));
typedef float f32x4  __attribute__((ext_vector_type(4)));

__device__ inline float bf2f(unsigned short u) {
    return __uint_as_float(((unsigned)u) << 16);
}
__device__ inline unsigned short f2bf(float f) {
    union { __hip_bfloat16 h; unsigned short u; } cv;
    cv.h = __float2bfloat16(f);
    return cv.u;
}

// ---------------- tiled fp32 GEMM (Phase A / legacy fallback) ---------------
template<bool BF16OUT>
__global__ __launch_bounds__(256) void gemm_f32(
    const float* __restrict__ A, const float* __restrict__ B,
    const float* __restrict__ bias, void* __restrict__ Cout,
    int M, int Nc, int K)
{
    __shared__ float As[16][68];
    __shared__ float Bs[16][68];
    const int t  = threadIdx.x;
    const int m0 = blockIdx.x * 64;
    const int n0 = blockIdx.y * 64;
    const int tx = t & 15;
    const int ty = t >> 4;
    const int lar = t >> 2;
    const int lac = (t & 3) * 4;
    const int lbr = t >> 4;
    const int lbc = (t & 15) * 4;

    float acc[4][4] = {};
    for (int k0 = 0; k0 < K; k0 += 16) {
        {
            int gr = m0 + lar;
            float4 v = make_float4(0.f, 0.f, 0.f, 0.f);
            if (gr < M) v = *reinterpret_cast<const float4*>(A + (size_t)gr * K + k0 + lac);
            As[lac + 0][lar] = v.x; As[lac + 1][lar] = v.y;
            As[lac + 2][lar] = v.z; As[lac + 3][lar] = v.w;
        }
        {
            float4 v = *reinterpret_cast<const float4*>(B + (size_t)(k0 + lbr) * Nc + n0 + lbc);
            *reinterpret_cast<float4*>(&Bs[lbr][lbc]) = v;
        }
        __syncthreads();
#pragma unroll
        for (int kk = 0; kk < 16; ++kk) {
            float a[4], b[4];
            *reinterpret_cast<float4*>(a) = *reinterpret_cast<const float4*>(&As[kk][ty * 4]);
            *reinterpret_cast<float4*>(b) = *reinterpret_cast<const float4*>(&Bs[kk][tx * 4]);
#pragma unroll
            for (int i = 0; i < 4; ++i)
#pragma unroll
                for (int j = 0; j < 4; ++j)
                    acc[i][j] = fmaf(a[i], b[j], acc[i][j]);
        }
        __syncthreads();
    }
    float bj[4] = {0.f, 0.f, 0.f, 0.f};
    if (bias) *reinterpret_cast<float4*>(bj) = *reinterpret_cast<const float4*>(bias + n0 + tx * 4);
#pragma unroll
    for (int i = 0; i < 4; ++i) {
        int row = m0 + ty * 4 + i;
        if (row < M) {
            float v0 = acc[i][0] + bj[0], v1 = acc[i][1] + bj[1];
            float v2 = acc[i][2] + bj[2], v3 = acc[i][3] + bj[3];
            if constexpr (BF16OUT) {
                unsigned short h[4] = { f2bf(v0), f2bf(v1), f2bf(v2), f2bf(v3) };
                *reinterpret_cast<uint2*>((unsigned short*)Cout + (size_t)row * Nc + n0 + tx * 4) =
                    *reinterpret_cast<uint2*>(h);
            } else {
                *reinterpret_cast<float4*>((float*)Cout + (size_t)row * Nc + n0 + tx * 4) =
                    make_float4(v0, v1, v2, v3);
            }
        }
    }
}

// ---------------- MFMA split-bf16 GEMM ---------------------------------------
// A frags: [mtile][KS][64 lanes][8], lane = ksub*16 + (row%16), k-contig 8/lane.
// B frags: [ctile][KS][64 lanes][8], lane = ksub*16 + (col%16).
// D: col = lane&15, row = mtile*16 + 4*(lane>>4) + r   [m89-verified layout].
template<int KS, bool BF16OUT>
__global__ __launch_bounds__(256) void mfma_gemm(
    const bf16x8* __restrict__ ahi, const bf16x8* __restrict__ alo,
    const bf16x8* __restrict__ bhi, const bf16x8* __restrict__ blo,
    const float* __restrict__ bias, void* __restrict__ out, int M, int Nc)
{
    const int wid  = threadIdx.x >> 6;
    const int lane = threadIdx.x & 63;
    const int mt   = blockIdx.x * 4 + wid;

    bf16x8 Ah[KS], Al[KS];
    size_t abase = (size_t)mt * KS * 64 + lane;
#pragma unroll
    for (int ks = 0; ks < KS; ++ks) {
        Ah[ks] = ahi[abase + ks * 64];
        Al[ks] = alo[abase + ks * 64];
    }
    const int NT    = Nc >> 4;
    const int colb  = lane & 15;
    const int rbase = mt * 16 + (lane >> 4) * 4;

    for (int ct = 0; ct < NT; ++ct) {
        f32x4 acc = {0.f, 0.f, 0.f, 0.f};
        size_t bbase = (size_t)ct * KS * 64 + lane;
#pragma unroll
        for (int ks = 0; ks < KS; ++ks) {
            bf16x8 Bh = bhi[bbase + ks * 64];
            bf16x8 Bl = blo[bbase + ks * 64];
            acc = __builtin_amdgcn_mfma_f32_16x16x32_bf16(Ah[ks], Bh, acc, 0, 0, 0);
            acc = __builtin_amdgcn_mfma_f32_16x16x32_bf16(Al[ks], Bh, acc, 0, 0, 0);
            acc = __builtin_amdgcn_mfma_f32_16x16x32_bf16(Ah[ks], Bl, acc, 0, 0, 0);
        }
        int col = ct * 16 + colb;
        float bv = bias ? bias[col] : 0.f;
#pragma unroll
        for (int r = 0; r < 4; ++r) {
            int row = rbase + r;
            if (row < M) {
                if constexpr (BF16OUT)
                    ((unsigned short*)out)[(size_t)row * Nc + col] = f2bf(acc[r] + bv);
                else
                    ((float*)out)[(size_t)row * Nc + col] = acc[r] + bv;
            }
        }
    }
}

// ---------------- weight pre-pack into B-fragment order ---------------------
__global__ void prepack_b(const float* __restrict__ B, unsigned short* __restrict__ bhi,
                          unsigned short* __restrict__ blo, int K, int Nc)
{
    int idx = blockIdx.x * 256 + threadIdx.x;
    if (idx >= K * Nc) return;
    int k = idx / Nc, col = idx - k * Nc;
    float v = B[idx];
    unsigned short hi = f2bf(v);
    unsigned short lo = f2bf(v - bf2f(hi));
    int KSp = K >> 5;
    int ct = col >> 4, cin = col & 15, ks = k >> 5, sub = (k >> 3) & 3, j = k & 7;
    size_t o = (((size_t)(ct * KSp + ks) * 4 + sub) * 16 + cin) * 8 + j;
    bhi[o] = hi; blo[o] = lo;
}

// ---------------- BN stats: per-column sum & sumsq in double ---------------
template<int C>
__global__ __launch_bounds__(256) void bn_stats(const float* __restrict__ y,
                                                double* __restrict__ sums, int Nn)
{
    constexpr int R = (256 / C) < 1 ? 1 : (256 / C);
    const int t = threadIdx.x;
    const int col = (C >= 256) ? t : (t % C);
    const int r0  = (C >= 256) ? 0 : (t / C);
    double s = 0.0, s2 = 0.0;
    for (int row = blockIdx.x * R + r0; row < Nn; row += gridDim.x * R) {
        float v = y[(size_t)row * C + col];
        s += v; s2 += (double)v * (double)v;
    }
    __shared__ double ls[256], ls2[256];
    ls[t] = s; ls2[t] = s2;
    __syncthreads();
    if (t < C) {
#pragma unroll
        for (int k = 1; k < R; ++k) { s += ls[t + k * C]; s2 += ls2[t + k * C]; }
        atomicAdd(&sums[col], s);
        atomicAdd(&sums[C + col], s2);
    }
}

template<int C>
__global__ void bn_fin(const double* __restrict__ sums, const float* __restrict__ g,
                       const float* __restrict__ be, float* __restrict__ sc,
                       float* __restrict__ sh, int Nn)
{
    int c = threadIdx.x;
    if (c < C) {
        double mean = sums[c] / Nn;
        double var  = sums[C + c] / Nn - mean * mean;
        if (var < 0.0) var = 0.0;
        double s = (double)g[c] / sqrt(var + 1e-5);
        sc[c] = (float)s;
        sh[c] = (float)((double)be[c] - mean * s);
    }
}

// in-place fp32 BN+ReLU (Phase D / legacy)
template<int C>
__global__ __launch_bounds__(256) void bn_apply_relu(float* __restrict__ y,
                                                     const float* __restrict__ sc,
                                                     const float* __restrict__ sh, int total4)
{
    int i = blockIdx.x * blockDim.x + threadIdx.x;
    int stride = gridDim.x * blockDim.x;
    for (; i < total4; i += stride) {
        float4 v = reinterpret_cast<float4*>(y)[i];
        int cb = (i * 4) % C;
        float4 s = *reinterpret_cast<const float4*>(sc + cb);
        float4 h = *reinterpret_cast<const float4*>(sh + cb);
        v.x = fmaxf(fmaf(v.x, s.x, h.x), 0.f);
        v.y = fmaxf(fmaf(v.y, s.y, h.y), 0.f);
        v.z = fmaxf(fmaf(v.z, s.z, h.z), 0.f);
        v.w = fmaxf(fmaf(v.w, s.w, h.w), 0.f);
        reinterpret_cast<float4*>(y)[i] = v;
    }
}

// BN+ReLU fused with hi/lo split + A-fragment packing. Pad rows -> zeros.
template<int C>
__global__ __launch_bounds__(256) void bn_apply_frag(
    const float* __restrict__ y, const float* __restrict__ sc,
    const float* __restrict__ sh, uint4* __restrict__ hhi,
    uint4* __restrict__ hlo, int M, int total /* Mpad*C/8 */)
{
    constexpr int G = C / 8;
    constexpr int KSp = C / 32;
    int g = blockIdx.x * 256 + threadIdx.x;
    if (g >= total) return;
    int row = g / G;
    int kb  = (g - row * G) * 8;
    unsigned short hi[8], lo[8];
    if (row < M) {
        const float* yp = y + (size_t)row * C + kb;
        float4 v0 = *reinterpret_cast<const float4*>(yp);
        float4 v1 = *reinterpret_cast<const float4*>(yp + 4);
        float4 s0 = *reinterpret_cast<const float4*>(sc + kb);
        float4 s1 = *reinterpret_cast<const float4*>(sc + kb + 4);
        float4 h0 = *reinterpret_cast<const float4*>(sh + kb);
        float4 h1 = *reinterpret_cast<const float4*>(sh + kb + 4);
        float r[8];
        r[0] = fmaxf(fmaf(v0.x, s0.x, h0.x), 0.f);
        r[1] = fmaxf(fmaf(v0.y, s0.y, h0.y), 0.f);
        r[2] = fmaxf(fmaf(v0.z, s0.z, h0.z), 0.f);
        r[3] = fmaxf(fmaf(v0.w, s0.w, h0.w), 0.f);
        r[4] = fmaxf(fmaf(v1.x, s1.x, h1.x), 0.f);
        r[5] = fmaxf(fmaf(v1.y, s1.y, h1.y), 0.f);
        r[6] = fmaxf(fmaf(v1.z, s1.z, h1.z), 0.f);
        r[7] = fmaxf(fmaf(v1.w, s1.w, h1.w), 0.f);
#pragma unroll
        for (int j = 0; j < 8; ++j) {
            hi[j] = f2bf(r[j]);
            lo[j] = f2bf(r[j] - bf2f(hi[j]));
        }
    } else {
#pragma unroll
        for (int j = 0; j < 8; ++j) { hi[j] = 0; lo[j] = 0; }
    }
    int mt = row >> 4, rin = row & 15, ks = kb >> 5, sub = (kb >> 3) & 3;
    size_t o = ((size_t)(mt * KSp + ks) * 4 + sub) * 16 + rin;
    hhi[o] = *reinterpret_cast<uint4*>(hi);
    hlo[o] = *reinterpret_cast<uint4*>(lo);
}

// ---------------- attention scores per node (bf16 features) ----------------
template<int HEADS>
__global__ __launch_bounds__(256) void att_scores(
    const __hip_bfloat16* __restrict__ g, const float* __restrict__ att_s,
    const float* __restrict__ att_d, float* __restrict__ a_s,
    float* __restrict__ a_d, int Nn)
{
    constexpr int C = HEADS * 128;
    constexpr int VEC = C / 64;
    constexpr int GROUP = 128 / VEC;
    int wid  = (blockIdx.x * 256 + threadIdx.x) >> 6;
    int lane = threadIdx.x & 63;
    if (wid >= Nn) return;
    float ps = 0.f, pd = 0.f;
    const __hip_bfloat16* gp = g + (size_t)wid * C + lane * VEC;
    unsigned short u[VEC];
    if constexpr (VEC == 4) *reinterpret_cast<uint2*>(u) = *reinterpret_cast<const uint2*>(gp);
    else                    *reinterpret_cast<unsigned*>(u) = *reinterpret_cast<const unsigned*>(gp);
#pragma unroll
    for (int j = 0; j < VEC; ++j) {
        float v = bf2f(u[j]);
        ps += v * att_s[lane * VEC + j];
        pd += v * att_d[lane * VEC + j];
    }
    for (int off = 1; off < GROUP; off <<= 1) {
        ps += __shfl_xor(ps, off, 64);
        pd += __shfl_xor(pd, off, 64);
    }
    if ((lane & (GROUP - 1)) == 0) {
        int head = (lane * VEC) >> 7;
        a_s[wid * HEADS + head] = ps;
        a_d[wid * HEADS + head] = pd;
    }
}

// ---------------- CSR build -------------------------------------------------
__global__ void count_edges(const int* __restrict__ ei, int E, int Nn, int* __restrict__ counts)
{
    int k = blockIdx.x * blockDim.x + threadIdx.x;
    if (k >= E + Nn) return;
    int d = (k < E) ? ei[E + k] : (k - E);
    atomicAdd(&counts[d], 1);
}

__global__ void scan_chunk_sum(const int* __restrict__ counts, int Nn, int* __restrict__ csum)
{
    __shared__ int sh[256];
    int i = blockIdx.x * 256 + threadIdx.x;
    sh[threadIdx.x] = (i < Nn) ? counts[i] : 0;
    __syncthreads();
    for (int off = 128; off > 0; off >>= 1) {
        if (threadIdx.x < off) sh[threadIdx.x] += sh[threadIdx.x + off];
        __syncthreads();
    }
    if (threadIdx.x == 0) csum[blockIdx.x] = sh[0];
}

__global__ void scan_chunks(const int* __restrict__ csum, int nchunks, int* __restrict__ coff,
                            int* __restrict__ offsets, int Nn, int Etot)
{
    __shared__ int sh[256];
    int t = threadIdx.x;
    int v = (t < nchunks) ? csum[t] : 0;
    sh[t] = v;
    __syncthreads();
    for (int off = 1; off < 256; off <<= 1) {
        int add = (t >= off) ? sh[t - off] : 0;
        __syncthreads();
        sh[t] += add;
        __syncthreads();
    }
    if (t < nchunks) coff[t] = sh[t] - v;
    if (t == 0) offsets[Nn] = Etot;
}

__global__ void scan_final(const int* __restrict__ counts, int Nn,
                           const int* __restrict__ coff, int* __restrict__ offsets)
{
    __shared__ int sh[256];
    int t = threadIdx.x;
    int i = blockIdx.x * 256 + t;
    int v = (i < Nn) ? counts[i] : 0;
    sh[t] = v;
    __syncthreads();
    for (int off = 1; off < 256; off <<= 1) {
        int add = (t >= off) ? sh[t - off] : 0;
        __syncthreads();
        sh[t] += add;
        __syncthreads();
    }
    if (i < Nn) offsets[i] = coff[blockIdx.x] + sh[t] - v;
}

__global__ void scatter_edges(const int* __restrict__ ei, int E, int Nn,
                              const int* __restrict__ offsets, int* __restrict__ cursor,
                              int* __restrict__ csr_src)
{
    int k = blockIdx.x * blockDim.x + threadIdx.x;
    if (k >= E + Nn) return;
    int s, d;
    if (k < E) { s = ei[k]; d = ei[E + k]; } else { s = k - E; d = k - E; }
    int pos = offsets[d] + atomicAdd(&cursor[d], 1);
    csr_src[pos] = s;
}

// ---------------- fused GAT: per-node max + softmax + aggregation -----------
template<int C, int HEADS>
__global__ __launch_bounds__(256) void gat_agg_fused(
    const __hip_bfloat16* __restrict__ hfeat,
    const float* __restrict__ a_s, const float* __restrict__ a_d,
    const int* __restrict__ offsets, const int* __restrict__ csr_src,
    const float* __restrict__ bias, float* __restrict__ out, int Nn)
{
    int wid  = (blockIdx.x * 256 + threadIdx.x) >> 6;
    int lane = threadIdx.x & 63;
    if (wid >= Nn) return;
    const int gid = lane >> 4;
    const int gl  = lane & 15;
    const int beg = offsets[wid], end = offsets[wid + 1];

    float ad[HEADS];
#pragma unroll
    for (int h = 0; h < HEADS; ++h) ad[h] = a_d[wid * HEADS + h];

    float m[HEADS];
#pragma unroll
    for (int h = 0; h < HEADS; ++h) m[h] = -1e30f;
    for (int p = beg + lane; p < end; p += 64) {
        int s = csr_src[p];
#pragma unroll
        for (int h = 0; h < HEADS; ++h) {
            float e = a_s[s * HEADS + h] + ad[h];
            e = (e > 0.f) ? e : 0.2f * e;
            m[h] = fmaxf(m[h], e);
        }
    }
    for (int off = 1; off < 64; off <<= 1) {
#pragma unroll
        for (int h = 0; h < HEADS; ++h) m[h] = fmaxf(m[h], __shfl_xor(m[h], off, 64));
    }

    float acc[HEADS][8];
#pragma unroll
    for (int h = 0; h < HEADS; ++h)
#pragma unroll
        for (int j = 0; j < 8; ++j) acc[h][j] = 0.f;
    float wsum[HEADS];
#pragma unroll
    for (int h = 0; h < HEADS; ++h) wsum[h] = 0.f;

    for (int p0 = beg; p0 < end; p0 += 4) {
        int p = p0 + gid;
        bool act = (p < end);
        int s = csr_src[act ? p : beg];
        float w[HEADS];
#pragma unroll
        for (int h = 0; h < HEADS; ++h) {
            float e = a_s[s * HEADS + h] + ad[h];
            e = (e > 0.f) ? e : 0.2f * e;
            w[h] = act ? __expf(e - m[h]) : 0.f;
            wsum[h] += w[h];
        }
        if (act) {
            const __hip_bfloat16* row = hfeat + (size_t)s * C;
#pragma unroll
            for (int h = 0; h < HEADS; ++h) {
                uint4 d = *reinterpret_cast<const uint4*>(row + h * 128 + gl * 8);
                float wh = w[h];
                acc[h][0] = fmaf(wh, bf2f((unsigned short)(d.x & 0xffff)), acc[h][0]);
                acc[h][1] = fmaf(wh, bf2f((unsigned short)(d.x >> 16)),    acc[h][1]);
                acc[h][2] = fmaf(wh, bf2f((unsigned short)(d.y & 0xffff)), acc[h][2]);
                acc[h][3] = fmaf(wh, bf2f((unsigned short)(d.y >> 16)),    acc[h][3]);
                acc[h][4] = fmaf(wh, bf2f((unsigned short)(d.z & 0xffff)), acc[h][4]);
                acc[h][5] = fmaf(wh, bf2f((unsigned short)(d.z >> 16)),    acc[h][5]);
                acc[h][6] = fmaf(wh, bf2f((unsigned short)(d.w & 0xffff)), acc[h][6]);
                acc[h][7] = fmaf(wh, bf2f((unsigned short)(d.w >> 16)),    acc[h][7]);
            }
        }
    }

#pragma unroll
    for (int off = 16; off < 64; off <<= 1) {
#pragma unroll
        for (int h = 0; h < HEADS; ++h) {
            wsum[h] += __shfl_xor(wsum[h], off, 64);
#pragma unroll
            for (int j = 0; j < 8; ++j) acc[h][j] += __shfl_xor(acc[h][j], off, 64);
        }
    }

    if (gid == 0) {
        float* op = out + (size_t)wid * C;
#pragma unroll
        for (int h = 0; h < HEADS; ++h) {
            float inv = 1.f / (wsum[h] + 1e-16f);
            const float* bp = bias + h * 128 + gl * 8;
            float4 v0 = make_float4(
                fmaf(acc[h][0], inv, bp[0]), fmaf(acc[h][1], inv, bp[1]),
                fmaf(acc[h][2], inv, bp[2]), fmaf(acc[h][3], inv, bp[3]));
            float4 v1 = make_float4(
                fmaf(acc[h][4], inv, bp[4]), fmaf(acc[h][5], inv, bp[5]),
                fmaf(acc[h][6], inv, bp[6]), fmaf(acc[h][7], inv, bp[7]));
            *reinterpret_cast<float4*>(op + h * 128 + gl * 8)     = v0;
            *reinterpret_cast<float4*>(op + h * 128 + gl * 8 + 4) = v1;
        }
    }
}

// ---------------- final dot (N,64)@(64,1) -----------------------------------
__global__ __launch_bounds__(256) void final_dot(const float* __restrict__ h3,
                                                 const float* __restrict__ w,
                                                 const float* __restrict__ b,
                                                 float* __restrict__ out, int Nn)
{
    int wid  = (blockIdx.x * 256 + threadIdx.x) >> 6;
    int lane = threadIdx.x & 63;
    if (wid >= Nn) return;
    float v = h3[(size_t)wid * 64 + lane] * w[lane];
    for (int off = 32; off > 0; off >>= 1) v += __shfl_xor(v, off, 64);
    if (lane == 0) out[wid] = v + b[0];
}

// ---------------------------------------------------------------------------
extern "C" void kernel_launch(void* const* d_in, const int* in_sizes, int n_in,
                              void* d_out, int out_size, void* d_ws, size_t ws_size,
                              hipStream_t stream)
{
    const float* x     = (const float*)d_in[0];
    const int*   ei    = (const int*)d_in[1];
    const float* W_in  = (const float*)d_in[2];
    const float* b_in  = (const float*)d_in[3];
    const float* g0    = (const float*)d_in[4];
    const float* be0   = (const float*)d_in[5];
    const float* W1    = (const float*)d_in[6];
    const float* as1   = (const float*)d_in[7];
    const float* ad1   = (const float*)d_in[8];
    const float* bias1 = (const float*)d_in[9];
    const float* g1    = (const float*)d_in[10];
    const float* be1   = (const float*)d_in[11];
    const float* W2    = (const float*)d_in[12];
    const float* as2   = (const float*)d_in[13];
    const float* ad2   = (const float*)d_in[14];
    const float* bias2 = (const float*)d_in[15];
    const float* g2    = (const float*)d_in[16];
    const float* be2   = (const float*)d_in[17];
    const float* Wf1   = (const float*)d_in[18];
    const float* bf1   = (const float*)d_in[19];
    const float* gf    = (const float*)d_in[20];
    const float* bef   = (const float*)d_in[21];
    const float* Wf2   = (const float*)d_in[22];
    const float* bf2   = (const float*)d_in[23];

    const int N    = in_sizes[0] / 16;     // 50000
    const int E    = in_sizes[1] / 2;      // 800000
    const int Etot = E + N;
    const int Mpad = ((N + 63) / 64) * 64; // 50048

    // ---- workspace layout ----
    char* ws = (char*)d_ws;
    size_t off = 0;
    auto alloc = [&](size_t bytes) {
        size_t o = off;
        off += (bytes + 255) & ~(size_t)255;
        return o;
    };
    float* buf0 = (float*)(ws + alloc((size_t)N * 128 * 4));          // y0/h0 / out2
    float* buf2 = (float*)(ws + alloc((size_t)N * 256 * 4));          // out1
    float* buf1 = (float*)(ws + alloc((size_t)N * 64 * 4));           // y3 / h3
    __hip_bfloat16* gbuf = (__hip_bfloat16*)(ws + alloc((size_t)N * 256 * 2)); // g1/g2 bf16
    float* a_s  = (float*)(ws + alloc((size_t)N * 2 * 4));
    float* a_d  = (float*)(ws + alloc((size_t)N * 2 * 4));
    int* offsets  = (int*)(ws + alloc((size_t)(N + 1) * 4));
    int* csr_src  = (int*)(ws + alloc((size_t)Etot * 4));
    int* csum     = (int*)(ws + alloc(256 * 4));
    int* coff     = (int*)(ws + alloc(256 * 4));
    float* scale  = (float*)(ws + alloc(256 * 4));
    float* shift  = (float*)(ws + alloc(256 * 4));
    size_t zone0 = off;                      // ---- zero zone start ----
    int* counts      = (int*)(ws + alloc((size_t)N * 4));
    int* cursor      = (int*)(ws + alloc((size_t)N * 4));
    double* sums0    = (double*)(ws + alloc(2 * 128 * 8));
    double* sums1    = (double*)(ws + alloc(2 * 256 * 8));
    double* sums2    = (double*)(ws + alloc(2 * 128 * 8));
    double* sums3    = (double*)(ws + alloc(2 * 64 * 8));
    size_t zone_bytes = off - zone0;
    // ---- MFMA-path buffers (allocated last; guarded by ws_size) ----
    uint4* hhi = (uint4*)(ws + alloc((size_t)Mpad * 256 * 2));
    uint4* hlo = (uint4*)(ws + alloc((size_t)Mpad * 256 * 2));
    unsigned short* b1hi = (unsigned short*)(ws + alloc(128 * 256 * 2));
    unsigned short* b1lo = (unsigned short*)(ws + alloc(128 * 256 * 2));
    unsigned short* b2hi = (unsigned short*)(ws + alloc(256 * 128 * 2));
    unsigned short* b2lo = (unsigned short*)(ws + alloc(256 * 128 * 2));
    unsigned short* bfhi = (unsigned short*)(ws + alloc(128 * 64 * 2));
    unsigned short* bflo = (unsigned short*)(ws + alloc(128 * 64 * 2));
    const bool use_mfma = (ws_size >= off);

    hipMemsetAsync(ws + zone0, 0, zone_bytes, stream);

    dim3 blk(256);
    const int gM  = (N + 63) / 64;
    const int gE  = (Etot + 255) / 256;
    const int gW  = (N + 3) / 4;
    const int nch = (N + 255) / 256;
    const int gMt = Mpad / 64;                       // mfma_gemm grid
    const int gF128 = (Mpad * 16 + 255) / 256;       // bn_apply_frag<128>
    const int gF256 = (Mpad * 32 + 255) / 256;       // bn_apply_frag<256>

    if (use_mfma) {
        // weight pre-pack (constant inputs; run every call for graph-capture parity)
        prepack_b<<<dim3((128 * 256 + 255) / 256), blk, 0, stream>>>(W1, b1hi, b1lo, 128, 256);
        prepack_b<<<dim3((256 * 128 + 255) / 256), blk, 0, stream>>>(W2, b2hi, b2lo, 256, 128);
        prepack_b<<<dim3((128 * 64 + 255) / 256),  blk, 0, stream>>>(Wf1, bfhi, bflo, 128, 64);
    }

    // ---- Phase A: y0 = x @ W_in + b_in; BN+ReLU -> h frags (or fp32) ----
    gemm_f32<false><<<dim3(gM, 2), blk, 0, stream>>>(x, W_in, b_in, buf0, N, 128, 16);
    bn_stats<128><<<dim3(400), blk, 0, stream>>>(buf0, sums0, N);
    bn_fin<128><<<1, 128, 0, stream>>>(sums0, g0, be0, scale, shift, N);
    if (use_mfma)
        bn_apply_frag<128><<<dim3(gF128), blk, 0, stream>>>(buf0, scale, shift, hhi, hlo, N, Mpad * 16);
    else
        bn_apply_relu<128><<<dim3(2048), blk, 0, stream>>>(buf0, scale, shift, N * 128 / 4);

    // ---- CSR build (reused by both GAT layers) ----
    count_edges<<<gE, blk, 0, stream>>>(ei, E, N, counts);
    scan_chunk_sum<<<nch, blk, 0, stream>>>(counts, N, csum);
    scan_chunks<<<1, blk, 0, stream>>>(csum, nch, coff, offsets, N, Etot);
    scan_final<<<nch, blk, 0, stream>>>(counts, N, coff, offsets);
    scatter_edges<<<gE, blk, 0, stream>>>(ei, E, N, offsets, cursor, csr_src);

    // ---- Phase B: GAT layer 1 (heads=2, C=256) ----
    if (use_mfma)
        mfma_gemm<4, true><<<dim3(gMt), blk, 0, stream>>>(
            (const bf16x8*)hhi, (const bf16x8*)hlo, (const bf16x8*)b1hi, (const bf16x8*)b1lo,
            nullptr, gbuf, N, 256);
    else
        gemm_f32<true><<<dim3(gM, 4), blk, 0, stream>>>(buf0, W1, nullptr, gbuf, N, 256, 128);
    att_scores<2><<<dim3(gW), blk, 0, stream>>>(gbuf, as1, ad1, a_s, a_d, N);
    gat_agg_fused<256, 2><<<dim3(gW), blk, 0, stream>>>(gbuf, a_s, a_d, offsets, csr_src, bias1, buf2, N);
    bn_stats<256><<<dim3(400), blk, 0, stream>>>(buf2, sums1, N);
    bn_fin<256><<<1, 256, 0, stream>>>(sums1, g1, be1, scale, shift, N);
    if (use_mfma)
        bn_apply_frag<256><<<dim3(gF256), blk, 0, stream>>>(buf2, scale, shift, hhi, hlo, N, Mpad * 32);
    else
        bn_apply_relu<256><<<dim3(2048), blk, 0, stream>>>(buf2, scale, shift, N * 256 / 4);

    // ---- Phase C: GAT layer 2 (heads=1, C=128) ----
    if (use_mfma)
        mfma_gemm<8, true><<<dim3(gMt), blk, 0, stream>>>(
            (const bf16x8*)hhi, (const bf16x8*)hlo, (const bf16x8*)b2hi, (const bf16x8*)b2lo,
            nullptr, gbuf, N, 128);
    else
        gemm_f32<true><<<dim3(gM, 2), blk, 0, stream>>>(buf2, W2, nullptr, gbuf, N, 128, 256);
    att_scores<1><<<dim3(gW), blk, 0, stream>>>(gbuf, as2, ad2, a_s, a_d, N);
    gat_agg_fused<128, 1><<<dim3(gW), blk, 0, stream>>>(gbuf, a_s, a_d, offsets, csr_src, bias2, buf0, N);
    bn_stats<128><<<dim3(400), blk, 0, stream>>>(buf0, sums2, N);
    bn_fin<128><<<1, 128, 0, stream>>>(sums2, g2, be2, scale, shift, N);
    if (use_mfma)
        bn_apply_frag<128><<<dim3(gF128), blk, 0, stream>>>(buf0, scale, shift, hhi, hlo, N, Mpad * 16);
    else
        bn_apply_relu<128><<<dim3(2048), blk, 0, stream>>>(buf0, scale, shift, N * 128 / 4);

    // ---- Phase D: y3 = h2 @ Wf1 + bf1; BN+ReLU (fp32) ----
    if (use_mfma)
        mfma_gemm<4, false><<<dim3(gMt), blk, 0, stream>>>(
            (const bf16x8*)hhi, (const bf16x8*)hlo, (const bf16x8*)bfhi, (const bf16x8*)bflo,
            bf1, buf1, N, 64);
    else
        gemm_f32<false><<<dim3(gM, 1), blk, 0, stream>>>(buf0, Wf1, bf1, buf1, N, 64, 128);
    bn_stats<64><<<dim3(400), blk, 0, stream>>>(buf1, sums3, N);
    bn_fin<64><<<1, 64, 0, stream>>>(sums3, gf, bef, scale, shift, N);
    bn_apply_relu<64><<<dim3(2048), blk, 0, stream>>>(buf1, scale, shift, N * 64 / 4);

    // ---- Phase E: out = h3 @ Wf2 + bf2 ----
    final_dot<<<dim3(gW), blk, 0, stream>>>(buf1, Wf2, bf2, (float*)d_out, N);
}